// Round 1
// baseline (1474.741 us; speedup 1.0000x reference)
//
#include <hip/hip_runtime.h>
#include <math.h>

#define HID 128
#define RBF 32
#define NL 6
#define BINS 4096
#define DMAXF 5.0f
#define INV_STEP (4096.0f / 5.0f)
#define GAMMAF 32.0f
#define CSPACE (4.0f / 31.0f)   // linspace(0,4,32) spacing

__device__ __forceinline__ float sspf(float x) {
    // softplus(x) - 0.5, stable
    return fmaxf(x, 0.0f) + log1pf(expf(-fabsf(x))) - 0.5f;
}

// ---------- one-time preprocessing ----------

__global__ void k_dist(const int* __restrict__ ei, const float* __restrict__ pos,
                       float* __restrict__ dist, int* __restrict__ counts, int E_) {
    int e = blockIdx.x * blockDim.x + threadIdx.x;
    if (e >= E_) return;
    int i = ei[e], j = ei[E_ + e];
    float dx = pos[3 * i]     - pos[3 * j];
    float dy = pos[3 * i + 1] - pos[3 * j + 1];
    float dz = pos[3 * i + 2] - pos[3 * j + 2];
    dist[e] = sqrtf(dx * dx + dy * dy + dz * dz);
    atomicAdd(&counts[i], 1);
}

#define SCAN_T 1024
__global__ void k_scan(const int* __restrict__ counts, int* __restrict__ row_ofs,
                       int* __restrict__ cursor, int n) {
    __shared__ int sums[SCAN_T];
    int tid = threadIdx.x;
    int chunk = (n + SCAN_T - 1) / SCAN_T;
    int base = tid * chunk;
    int s = 0;
    for (int k = 0; k < chunk; ++k) {
        int idx = base + k;
        if (idx < n) s += counts[idx];
    }
    sums[tid] = s;
    __syncthreads();
    for (int off = 1; off < SCAN_T; off <<= 1) {
        int v = 0;
        if (tid >= off) v = sums[tid - off];
        __syncthreads();
        if (tid >= off) sums[tid] += v;
        __syncthreads();
    }
    int run = (tid == 0) ? 0 : sums[tid - 1];
    for (int k = 0; k < chunk; ++k) {
        int idx = base + k;
        if (idx < n) {
            row_ofs[idx] = run;
            cursor[idx] = run;
            run += counts[idx];
        }
    }
    if (tid == SCAN_T - 1) row_ofs[n] = sums[SCAN_T - 1];
}

__global__ void k_scatter(const int* __restrict__ ei, const float* __restrict__ dist,
                          int* __restrict__ cursor, int* __restrict__ sj,
                          float* __restrict__ sdist, int E_) {
    int e = blockIdx.x * blockDim.x + threadIdx.x;
    if (e >= E_) return;
    int i = ei[e];
    int p = atomicAdd(&cursor[i], 1);
    sj[p] = ei[E_ + e];
    sdist[p] = dist[e];
}

__global__ void k_hinit(const int* __restrict__ z, const float* __restrict__ embed,
                        float* __restrict__ h, int total4) {
    int idx = blockIdx.x * blockDim.x + threadIdx.x;
    if (idx >= total4) return;
    int node = idx >> 5, q = idx & 31;
    ((float4*)h)[idx] = ((const float4*)embed)[(size_t)z[node] * 32 + q];
}

__global__ void k_invdeg(const int* __restrict__ counts, float* __restrict__ invdeg, int n) {
    int i = blockIdx.x * blockDim.x + threadIdx.x;
    if (i < n) invdeg[i] = 1.0f / fmaxf((float)counts[i], 1.0f);
}

// W(d) lookup tables: for each layer, (BINS+1) rows of 128 — W = ssp(rbf@fw1+fb1)@fw2+fb2
__global__ void k_tables(const float* __restrict__ fw1, const float* __restrict__ fb1,
                         const float* __restrict__ fw2, const float* __restrict__ fb2,
                         float* __restrict__ tables) {
    int l = blockIdx.x / (BINS + 1);
    int bin = blockIdx.x % (BINS + 1);
    int c = threadIdx.x;
    __shared__ float rbf[RBF];
    __shared__ float P[HID];
    float d = (float)bin * (DMAXF / (float)BINS);
    if (c < RBF) {
        float dd = d - (float)c * CSPACE;
        rbf[c] = expf(-GAMMAF * dd * dd);
    }
    __syncthreads();
    float u = fb1[l * HID + c];
#pragma unroll 8
    for (int r = 0; r < RBF; ++r) u += rbf[r] * fw1[((size_t)l * RBF + r) * HID + c];
    P[c] = sspf(u);
    __syncthreads();
    float w = fb2[l * HID + c];
#pragma unroll 8
    for (int k = 0; k < HID; ++k) w += P[k] * fw2[((size_t)l * HID + k) * HID + c];
    tables[((size_t)l * (BINS + 1) + bin) * HID + c] = w;
}

// ---------- per-layer edge pass: one wave per node, CSR, no atomics ----------
__global__ void k_edge(const int* __restrict__ row_ofs, const int* __restrict__ sj,
                       const float* __restrict__ sdist, const float* __restrict__ h,
                       const float* __restrict__ table, const float* __restrict__ invdeg,
                       float* __restrict__ aggr, int n) {
    int wv = (blockIdx.x * blockDim.x + threadIdx.x) >> 6;
    if (wv >= n) return;
    int lane = threadIdx.x & 63;
    int half = lane >> 5;   // two edges in flight per wave
    int sub = lane & 31;    // float4 channel block: c = 4*sub .. 4*sub+3
    int beg = row_ofs[wv], end = row_ofs[wv + 1];
    float4 acc = make_float4(0.f, 0.f, 0.f, 0.f);
    const float* hB = h + 4 * sub;
    const float* tB = table + 4 * sub;
    for (int k = beg + half; k < end; k += 2) {
        int j = sj[k];
        float d = sdist[k];
        float t = fminf(d, DMAXF) * INV_STEP;
        int b = (int)t;
        b = b < (BINS - 1) ? b : (BINS - 1);
        float f = t - (float)b;
        float4 hj = *(const float4*)(hB + (size_t)j * HID);
        const float* t0 = tB + (size_t)b * HID;
        float4 w0 = *(const float4*)t0;
        float4 w1 = *(const float4*)(t0 + HID);
        acc.x += hj.x * (w0.x + f * (w1.x - w0.x));
        acc.y += hj.y * (w0.y + f * (w1.y - w0.y));
        acc.z += hj.z * (w0.z + f * (w1.z - w0.z));
        acc.w += hj.w * (w0.w + f * (w1.w - w0.w));
    }
    acc.x += __shfl_xor(acc.x, 32);
    acc.y += __shfl_xor(acc.y, 32);
    acc.z += __shfl_xor(acc.z, 32);
    acc.w += __shfl_xor(acc.w, 32);
    if (half == 0) {
        float s = invdeg[wv];
        acc.x *= s; acc.y *= s; acc.z *= s; acc.w *= s;
        *(float4*)(aggr + (size_t)wv * HID + 4 * sub) = acc;
    }
}

// ---------- fused 2-layer MLP: Y = [ssp](ssp(X@W1+b1)@W2+b2) ----------
template <bool SSP2>
__global__ __launch_bounds__(256) void k_mlp(const float* __restrict__ X,
                                             const float* __restrict__ W1,
                                             const float* __restrict__ b1,
                                             const float* __restrict__ W2,
                                             const float* __restrict__ b2,
                                             float* __restrict__ Y, int M) {
    __shared__ float A[64][132];
    __shared__ float Bc[32][132];
    const int tid = threadIdx.x;
    const int tc = tid & 15, tr = tid >> 4;
    const int row0 = blockIdx.x * 64;
    const int c0 = tc * 8;

    // stage X tile (zero-padded past M)
    for (int t = tid; t < 2048; t += 256) {
        int r = t >> 5, q = t & 31;
        float4 v = make_float4(0.f, 0.f, 0.f, 0.f);
        if (row0 + r < M) v = *(const float4*)(X + (size_t)(row0 + r) * HID + q * 4);
        *(float4*)&A[r][q * 4] = v;
    }

    float acc[4][8];
    float bb[8];

    // ---- phase 1: X @ W1 + b1 ----
#pragma unroll
    for (int m = 0; m < 8; ++m) bb[m] = b1[c0 + m];
#pragma unroll
    for (int i = 0; i < 4; ++i)
#pragma unroll
        for (int m = 0; m < 8; ++m) acc[i][m] = bb[m];

    for (int kc = 0; kc < 4; ++kc) {
        __syncthreads();  // covers A staging (kc=0) and Bc reuse
        for (int t = tid; t < 1024; t += 256) {
            int r = t >> 5, q = t & 31;
            *(float4*)&Bc[r][q * 4] = *(const float4*)(W1 + (size_t)(kc * 32 + r) * HID + q * 4);
        }
        __syncthreads();
#pragma unroll 4
        for (int kk = 0; kk < 32; ++kk) {
            float a0 = A[tr * 4 + 0][kc * 32 + kk];
            float a1 = A[tr * 4 + 1][kc * 32 + kk];
            float a2 = A[tr * 4 + 2][kc * 32 + kk];
            float a3 = A[tr * 4 + 3][kc * 32 + kk];
            float4 bv0 = *(float4*)&Bc[kk][c0];
            float4 bv1 = *(float4*)&Bc[kk][c0 + 4];
            float bv[8] = {bv0.x, bv0.y, bv0.z, bv0.w, bv1.x, bv1.y, bv1.z, bv1.w};
#pragma unroll
            for (int m = 0; m < 8; ++m) {
                acc[0][m] += a0 * bv[m];
                acc[1][m] += a1 * bv[m];
                acc[2][m] += a2 * bv[m];
                acc[3][m] += a3 * bv[m];
            }
        }
    }
    __syncthreads();  // all A reads done before overwrite
    // t1 = ssp(acc) back into A
#pragma unroll
    for (int i = 0; i < 4; ++i)
#pragma unroll
        for (int m = 0; m < 8; ++m) A[tr * 4 + i][c0 + m] = sspf(acc[i][m]);

    // ---- phase 2: t1 @ W2 + b2 ----
#pragma unroll
    for (int m = 0; m < 8; ++m) bb[m] = b2[c0 + m];
#pragma unroll
    for (int i = 0; i < 4; ++i)
#pragma unroll
        for (int m = 0; m < 8; ++m) acc[i][m] = bb[m];

    for (int kc = 0; kc < 4; ++kc) {
        __syncthreads();  // covers t1 writes (kc=0) and Bc reuse
        for (int t = tid; t < 1024; t += 256) {
            int r = t >> 5, q = t & 31;
            *(float4*)&Bc[r][q * 4] = *(const float4*)(W2 + (size_t)(kc * 32 + r) * HID + q * 4);
        }
        __syncthreads();
#pragma unroll 4
        for (int kk = 0; kk < 32; ++kk) {
            float a0 = A[tr * 4 + 0][kc * 32 + kk];
            float a1 = A[tr * 4 + 1][kc * 32 + kk];
            float a2 = A[tr * 4 + 2][kc * 32 + kk];
            float a3 = A[tr * 4 + 3][kc * 32 + kk];
            float4 bv0 = *(float4*)&Bc[kk][c0];
            float4 bv1 = *(float4*)&Bc[kk][c0 + 4];
            float bv[8] = {bv0.x, bv0.y, bv0.z, bv0.w, bv1.x, bv1.y, bv1.z, bv1.w};
#pragma unroll
            for (int m = 0; m < 8; ++m) {
                acc[0][m] += a0 * bv[m];
                acc[1][m] += a1 * bv[m];
                acc[2][m] += a2 * bv[m];
                acc[3][m] += a3 * bv[m];
            }
        }
    }

#pragma unroll
    for (int i = 0; i < 4; ++i) {
        int r = row0 + tr * 4 + i;
        if (r < M) {
            float o[8];
#pragma unroll
            for (int m = 0; m < 8; ++m) o[m] = SSP2 ? sspf(acc[i][m]) : acc[i][m];
            *(float4*)(Y + (size_t)r * HID + c0)     = make_float4(o[0], o[1], o[2], o[3]);
            *(float4*)(Y + (size_t)r * HID + c0 + 4) = make_float4(o[4], o[5], o[6], o[7]);
        }
    }
}

// ---------- output: e_atom = E2 @ ow3 + ob3, summed per graph ----------
__global__ void k_energy(const float* __restrict__ E2, const float* __restrict__ ow3,
                         const float* __restrict__ ob3, const int* __restrict__ batch,
                         float* __restrict__ out, int n) {
    int wv = (blockIdx.x * blockDim.x + threadIdx.x) >> 6;
    if (wv >= n) return;
    int lane = threadIdx.x & 63;
    float2 v = *(const float2*)(E2 + (size_t)wv * HID + 2 * lane);
    float s = v.x * ow3[2 * lane] + v.y * ow3[2 * lane + 1];
#pragma unroll
    for (int o = 32; o > 0; o >>= 1) s += __shfl_xor(s, o);
    if (lane == 0) atomicAdd(&out[batch[wv]], s + ob3[0]);
}

extern "C" void kernel_launch(void* const* d_in, const int* in_sizes, int n_in,
                              void* d_out, int out_size, void* d_ws, size_t ws_size,
                              hipStream_t stream) {
    const int*   z     = (const int*)d_in[0];
    const float* pos   = (const float*)d_in[1];
    const int*   ei    = (const int*)d_in[2];
    const int*   batch = (const int*)d_in[3];
    const float* embed = (const float*)d_in[4];
    const float* fw1   = (const float*)d_in[5];
    const float* fb1   = (const float*)d_in[6];
    const float* fw2   = (const float*)d_in[7];
    const float* fb2   = (const float*)d_in[8];
    const float* uw1   = (const float*)d_in[9];
    const float* ub1   = (const float*)d_in[10];
    const float* uw2   = (const float*)d_in[11];
    const float* ub2   = (const float*)d_in[12];
    const float* ow1   = (const float*)d_in[13];
    const float* ob1   = (const float*)d_in[14];
    const float* ow2   = (const float*)d_in[15];
    const float* ob2   = (const float*)d_in[16];
    const float* ow3   = (const float*)d_in[17];
    const float* ob3   = (const float*)d_in[18];

    const int N = in_sizes[0];
    const int E = in_sizes[2] / 2;

    // workspace carve (~74.5 MB total)
    char* p = (char*)d_ws;
    auto alloc = [&](size_t bytes) {
        char* r = p;
        p += (bytes + 255) & ~(size_t)255;
        return r;
    };
    float* h       = (float*)alloc((size_t)N * HID * 4);
    float* aggr    = (float*)alloc((size_t)N * HID * 4);
    float* dist    = (float*)alloc((size_t)E * 4);
    int*   sj      = (int*)alloc((size_t)E * 4);
    float* sdist   = (float*)alloc((size_t)E * 4);
    int*   counts  = (int*)alloc((size_t)N * 4);
    int*   row_ofs = (int*)alloc((size_t)(N + 1) * 4);
    int*   cursor  = (int*)alloc((size_t)N * 4);
    float* invdeg  = (float*)alloc((size_t)N * 4);
    float* tables  = (float*)alloc((size_t)NL * (BINS + 1) * HID * 4);

    const int TB = 256;
    hipMemsetAsync(counts, 0, (size_t)N * 4, stream);
    hipMemsetAsync(d_out, 0, (size_t)out_size * sizeof(float), stream);

    k_dist<<<(E + TB - 1) / TB, TB, 0, stream>>>(ei, pos, dist, counts, E);
    k_scan<<<1, SCAN_T, 0, stream>>>(counts, row_ofs, cursor, N);
    k_scatter<<<(E + TB - 1) / TB, TB, 0, stream>>>(ei, dist, cursor, sj, sdist, E);
    int tot4 = N * 32;
    k_hinit<<<(tot4 + TB - 1) / TB, TB, 0, stream>>>(z, embed, h, tot4);
    k_invdeg<<<(N + TB - 1) / TB, TB, 0, stream>>>(counts, invdeg, N);
    k_tables<<<NL * (BINS + 1), HID, 0, stream>>>(fw1, fb1, fw2, fb2, tables);

    int eblocks = (N + 3) / 4;      // 4 waves per 256-thread block, 1 wave per node
    int mblocks = (N + 63) / 64;

    for (int l = 0; l < NL; ++l) {
        k_edge<<<eblocks, TB, 0, stream>>>(row_ofs, sj, sdist, h,
                                           tables + (size_t)l * (BINS + 1) * HID,
                                           invdeg, aggr, N);
        k_mlp<false><<<mblocks, TB, 0, stream>>>(aggr,
                                                 uw1 + (size_t)l * HID * HID, ub1 + (size_t)l * HID,
                                                 uw2 + (size_t)l * HID * HID, ub2 + (size_t)l * HID,
                                                 h, N);
    }
    // output block: two ssp layers into aggr (scratch), then dot + segment sum
    k_mlp<true><<<mblocks, TB, 0, stream>>>(h, ow1, ob1, ow2, ob2, aggr, N);
    k_energy<<<eblocks, TB, 0, stream>>>(aggr, ow3, ob3, batch, (float*)d_out, N);
}

// Round 2
// 1360.368 us; speedup vs baseline: 1.0841x; 1.0841x over previous
//
#include <hip/hip_runtime.h>
#include <hip/hip_fp16.h>
#include <math.h>

#define HID 128
#define RBF 32
#define NL 6
#define BINS 4096
#define DMAXF 5.0f
#define INV_STEP (4096.0f / 5.0f)
#define GAMMAF 32.0f
#define CSPACE (4.0f / 31.0f)   // linspace(0,4,32) spacing

__device__ __forceinline__ float sspf(float x) {
    // softplus(x) - 0.5, stable
    return fmaxf(x, 0.0f) + log1pf(expf(-fabsf(x))) - 0.5f;
}

// ---------- one-time preprocessing ----------

__global__ void k_dist(const int* __restrict__ ei, const float* __restrict__ pos,
                       float* __restrict__ dist, int* __restrict__ counts, int E_) {
    int e = blockIdx.x * blockDim.x + threadIdx.x;
    if (e >= E_) return;
    int i = ei[e], j = ei[E_ + e];
    float dx = pos[3 * i]     - pos[3 * j];
    float dy = pos[3 * i + 1] - pos[3 * j + 1];
    float dz = pos[3 * i + 2] - pos[3 * j + 2];
    dist[e] = sqrtf(dx * dx + dy * dy + dz * dz);
    atomicAdd(&counts[i], 1);
}

// hierarchical exclusive scan: 256-elem blocks -> block sums -> apply
#define SB 256
__global__ void k_scan1(const int* __restrict__ counts, int* __restrict__ pre,
                        int* __restrict__ bsums, int n) {
    __shared__ int s[SB];
    int tid = threadIdx.x;
    int g = blockIdx.x * SB + tid;
    int v = (g < n) ? counts[g] : 0;
    s[tid] = v;
    __syncthreads();
    for (int off = 1; off < SB; off <<= 1) {
        int t = (tid >= off) ? s[tid - off] : 0;
        __syncthreads();
        s[tid] += t;
        __syncthreads();
    }
    if (g < n) pre[g] = s[tid] - v;   // exclusive within block
    if (tid == SB - 1) bsums[blockIdx.x] = s[tid];
}

__global__ void k_scan2(int* __restrict__ bsums, int nb) {
    __shared__ int s[1024];
    int tid = threadIdx.x;
    int v = (tid < nb) ? bsums[tid] : 0;
    s[tid] = v;
    __syncthreads();
    for (int off = 1; off < 1024; off <<= 1) {
        int t = (tid >= off) ? s[tid - off] : 0;
        __syncthreads();
        s[tid] += t;
        __syncthreads();
    }
    if (tid < nb) bsums[tid] = s[tid] - v;  // exclusive block offsets
}

__global__ void k_scan3(const int* __restrict__ pre, const int* __restrict__ bsums,
                        const int* __restrict__ counts, int* __restrict__ row_ofs,
                        int* __restrict__ cursor, int n) {
    int g = blockIdx.x * SB + threadIdx.x;
    if (g >= n) return;
    int r = pre[g] + bsums[g >> 8];
    row_ofs[g] = r;
    cursor[g] = r;
    if (g == n - 1) row_ofs[n] = r + counts[g];
}

__global__ void k_scatter(const int* __restrict__ ei, const float* __restrict__ dist,
                          int* __restrict__ cursor, int* __restrict__ sj,
                          float* __restrict__ sdist, int E_) {
    int e = blockIdx.x * blockDim.x + threadIdx.x;
    if (e >= E_) return;
    int i = ei[e];
    int p = atomicAdd(&cursor[i], 1);
    sj[p] = ei[E_ + e];
    sdist[p] = dist[e];
}

__global__ void k_hinit(const int* __restrict__ z, const float* __restrict__ embed,
                        float* __restrict__ h, int total4) {
    int idx = blockIdx.x * blockDim.x + threadIdx.x;
    if (idx >= total4) return;
    int node = idx >> 5, q = idx & 31;
    ((float4*)h)[idx] = ((const float4*)embed)[(size_t)z[node] * 32 + q];
}

__global__ void k_invdeg(const int* __restrict__ counts, float* __restrict__ invdeg, int n) {
    int i = blockIdx.x * blockDim.x + threadIdx.x;
    if (i < n) invdeg[i] = 1.0f / fmaxf((float)counts[i], 1.0f);
}

// W(d) tables (fp32): for each layer, (BINS+1) rows of 128 — W = ssp(rbf@fw1+fb1)@fw2+fb2
__global__ void k_tables(const float* __restrict__ fw1, const float* __restrict__ fb1,
                         const float* __restrict__ fw2, const float* __restrict__ fb2,
                         float* __restrict__ tables) {
    int l = blockIdx.x / (BINS + 1);
    int bin = blockIdx.x % (BINS + 1);
    int c = threadIdx.x;
    __shared__ float rbf[RBF];
    __shared__ float P[HID];
    float d = (float)bin * (DMAXF / (float)BINS);
    if (c < RBF) {
        float dd = d - (float)c * CSPACE;
        rbf[c] = expf(-GAMMAF * dd * dd);
    }
    __syncthreads();
    float u = fb1[l * HID + c];
#pragma unroll 8
    for (int r = 0; r < RBF; ++r) u += rbf[r] * fw1[((size_t)l * RBF + r) * HID + c];
    P[c] = sspf(u);
    __syncthreads();
    float w = fb2[l * HID + c];
#pragma unroll 8
    for (int k = 0; k < HID; ++k) w += P[k] * fw2[((size_t)l * HID + k) * HID + c];
    tables[((size_t)l * (BINS + 1) + bin) * HID + c] = w;
}

// pack interleaved lerp endpoints: packed[l][b][c] = half2(W[b][c], W[b+1][c])
__global__ void k_pack(const float* __restrict__ tabf, __half2* __restrict__ packed) {
    int l = blockIdx.x / BINS, b = blockIdx.x % BINS;
    int c = threadIdx.x;
    const float* row = tabf + ((size_t)l * (BINS + 1) + b) * HID + c;
    packed[((size_t)l * BINS + b) * HID + c] = __floats2half2_rn(row[0], row[HID]);
}

// ---------- per-layer edge pass: one wave per node, CSR, no atomics ----------
// table: half2-interleaved (w_b, w_{b+1}) per channel — one 16B load gives 4 channels' lerp pair
__global__ void k_edge(const int* __restrict__ row_ofs, const int* __restrict__ sj,
                       const float* __restrict__ sdist, const float* __restrict__ h,
                       const __half2* __restrict__ table, const float* __restrict__ invdeg,
                       float* __restrict__ aggr, int n) {
    int wv = (blockIdx.x * blockDim.x + threadIdx.x) >> 6;
    if (wv >= n) return;
    int lane = threadIdx.x & 63;
    int half = lane >> 5;   // two edges in flight per wave
    int sub = lane & 31;    // float4 channel block: c = 4*sub .. 4*sub+3
    int beg = row_ofs[wv], end = row_ofs[wv + 1];
    float4 acc = make_float4(0.f, 0.f, 0.f, 0.f);
    const float* hB = h + 4 * sub;
    const __half2* tB = table + 4 * sub;
    for (int k = beg + half; k < end; k += 2) {
        int j = sj[k];
        float d = sdist[k];
        float t = fminf(d, DMAXF) * INV_STEP;
        int b = (int)t;
        b = b < (BINS - 1) ? b : (BINS - 1);
        float f = t - (float)b;
        float4 hj = *(const float4*)(hB + (size_t)j * HID);
        float4 tw = *(const float4*)(tB + (size_t)b * HID);
        float2 p0 = __half22float2(*(__half2*)&tw.x);
        float2 p1 = __half22float2(*(__half2*)&tw.y);
        float2 p2 = __half22float2(*(__half2*)&tw.z);
        float2 p3 = __half22float2(*(__half2*)&tw.w);
        acc.x += hj.x * (p0.x + f * (p0.y - p0.x));
        acc.y += hj.y * (p1.x + f * (p1.y - p1.x));
        acc.z += hj.z * (p2.x + f * (p2.y - p2.x));
        acc.w += hj.w * (p3.x + f * (p3.y - p3.x));
    }
    acc.x += __shfl_xor(acc.x, 32);
    acc.y += __shfl_xor(acc.y, 32);
    acc.z += __shfl_xor(acc.z, 32);
    acc.w += __shfl_xor(acc.w, 32);
    if (half == 0) {
        float s = invdeg[wv];
        acc.x *= s; acc.y *= s; acc.z *= s; acc.w *= s;
        *(float4*)(aggr + (size_t)wv * HID + 4 * sub) = acc;
    }
}

// ---------- fused 2-layer MLP: Y = [ssp](ssp(X@W1+b1)@W2+b2) ----------
template <bool SSP2>
__global__ __launch_bounds__(256) void k_mlp(const float* __restrict__ X,
                                             const float* __restrict__ W1,
                                             const float* __restrict__ b1,
                                             const float* __restrict__ W2,
                                             const float* __restrict__ b2,
                                             float* __restrict__ Y, int M) {
    __shared__ float A[64][132];
    __shared__ float Bc[32][132];
    const int tid = threadIdx.x;
    const int tc = tid & 15, tr = tid >> 4;
    const int row0 = blockIdx.x * 64;
    const int c0 = tc * 8;

    // stage X tile (zero-padded past M)
    for (int t = tid; t < 2048; t += 256) {
        int r = t >> 5, q = t & 31;
        float4 v = make_float4(0.f, 0.f, 0.f, 0.f);
        if (row0 + r < M) v = *(const float4*)(X + (size_t)(row0 + r) * HID + q * 4);
        *(float4*)&A[r][q * 4] = v;
    }

    float acc[4][8];
    float bb[8];

    // ---- phase 1: X @ W1 + b1 ----
#pragma unroll
    for (int m = 0; m < 8; ++m) bb[m] = b1[c0 + m];
#pragma unroll
    for (int i = 0; i < 4; ++i)
#pragma unroll
        for (int m = 0; m < 8; ++m) acc[i][m] = bb[m];

    for (int kc = 0; kc < 4; ++kc) {
        __syncthreads();  // covers A staging (kc=0) and Bc reuse
        for (int t = tid; t < 1024; t += 256) {
            int r = t >> 5, q = t & 31;
            *(float4*)&Bc[r][q * 4] = *(const float4*)(W1 + (size_t)(kc * 32 + r) * HID + q * 4);
        }
        __syncthreads();
#pragma unroll 4
        for (int kk = 0; kk < 32; ++kk) {
            float a0 = A[tr * 4 + 0][kc * 32 + kk];
            float a1 = A[tr * 4 + 1][kc * 32 + kk];
            float a2 = A[tr * 4 + 2][kc * 32 + kk];
            float a3 = A[tr * 4 + 3][kc * 32 + kk];
            float4 bv0 = *(float4*)&Bc[kk][c0];
            float4 bv1 = *(float4*)&Bc[kk][c0 + 4];
            float bv[8] = {bv0.x, bv0.y, bv0.z, bv0.w, bv1.x, bv1.y, bv1.z, bv1.w};
#pragma unroll
            for (int m = 0; m < 8; ++m) {
                acc[0][m] += a0 * bv[m];
                acc[1][m] += a1 * bv[m];
                acc[2][m] += a2 * bv[m];
                acc[3][m] += a3 * bv[m];
            }
        }
    }
    __syncthreads();  // all A reads done before overwrite
    // t1 = ssp(acc) back into A
#pragma unroll
    for (int i = 0; i < 4; ++i)
#pragma unroll
        for (int m = 0; m < 8; ++m) A[tr * 4 + i][c0 + m] = sspf(acc[i][m]);

    // ---- phase 2: t1 @ W2 + b2 ----
#pragma unroll
    for (int m = 0; m < 8; ++m) bb[m] = b2[c0 + m];
#pragma unroll
    for (int i = 0; i < 4; ++i)
#pragma unroll
        for (int m = 0; m < 8; ++m) acc[i][m] = bb[m];

    for (int kc = 0; kc < 4; ++kc) {
        __syncthreads();  // covers t1 writes (kc=0) and Bc reuse
        for (int t = tid; t < 1024; t += 256) {
            int r = t >> 5, q = t & 31;
            *(float4*)&Bc[r][q * 4] = *(const float4*)(W2 + (size_t)(kc * 32 + r) * HID + q * 4);
        }
        __syncthreads();
#pragma unroll 4
        for (int kk = 0; kk < 32; ++kk) {
            float a0 = A[tr * 4 + 0][kc * 32 + kk];
            float a1 = A[tr * 4 + 1][kc * 32 + kk];
            float a2 = A[tr * 4 + 2][kc * 32 + kk];
            float a3 = A[tr * 4 + 3][kc * 32 + kk];
            float4 bv0 = *(float4*)&Bc[kk][c0];
            float4 bv1 = *(float4*)&Bc[kk][c0 + 4];
            float bv[8] = {bv0.x, bv0.y, bv0.z, bv0.w, bv1.x, bv1.y, bv1.z, bv1.w};
#pragma unroll
            for (int m = 0; m < 8; ++m) {
                acc[0][m] += a0 * bv[m];
                acc[1][m] += a1 * bv[m];
                acc[2][m] += a2 * bv[m];
                acc[3][m] += a3 * bv[m];
            }
        }
    }

#pragma unroll
    for (int i = 0; i < 4; ++i) {
        int r = row0 + tr * 4 + i;
        if (r < M) {
            float o[8];
#pragma unroll
            for (int m = 0; m < 8; ++m) o[m] = SSP2 ? sspf(acc[i][m]) : acc[i][m];
            *(float4*)(Y + (size_t)r * HID + c0)     = make_float4(o[0], o[1], o[2], o[3]);
            *(float4*)(Y + (size_t)r * HID + c0 + 4) = make_float4(o[4], o[5], o[6], o[7]);
        }
    }
}

// ---------- output: e_atom = E2 @ ow3 + ob3, summed per graph ----------
__global__ void k_energy(const float* __restrict__ E2, const float* __restrict__ ow3,
                         const float* __restrict__ ob3, const int* __restrict__ batch,
                         float* __restrict__ out, int n) {
    int wv = (blockIdx.x * blockDim.x + threadIdx.x) >> 6;
    if (wv >= n) return;
    int lane = threadIdx.x & 63;
    float2 v = *(const float2*)(E2 + (size_t)wv * HID + 2 * lane);
    float s = v.x * ow3[2 * lane] + v.y * ow3[2 * lane + 1];
#pragma unroll
    for (int o = 32; o > 0; o >>= 1) s += __shfl_xor(s, o);
    if (lane == 0) atomicAdd(&out[batch[wv]], s + ob3[0]);
}

extern "C" void kernel_launch(void* const* d_in, const int* in_sizes, int n_in,
                              void* d_out, int out_size, void* d_ws, size_t ws_size,
                              hipStream_t stream) {
    const int*   z     = (const int*)d_in[0];
    const float* pos   = (const float*)d_in[1];
    const int*   ei    = (const int*)d_in[2];
    const int*   batch = (const int*)d_in[3];
    const float* embed = (const float*)d_in[4];
    const float* fw1   = (const float*)d_in[5];
    const float* fb1   = (const float*)d_in[6];
    const float* fw2   = (const float*)d_in[7];
    const float* fb2   = (const float*)d_in[8];
    const float* uw1   = (const float*)d_in[9];
    const float* ub1   = (const float*)d_in[10];
    const float* uw2   = (const float*)d_in[11];
    const float* ub2   = (const float*)d_in[12];
    const float* ow1   = (const float*)d_in[13];
    const float* ob1   = (const float*)d_in[14];
    const float* ow2   = (const float*)d_in[15];
    const float* ob2   = (const float*)d_in[16];
    const float* ow3   = (const float*)d_in[17];
    const float* ob3   = (const float*)d_in[18];

    const int N = in_sizes[0];
    const int E = in_sizes[2] / 2;
    const int NB = (N + SB - 1) / SB;   // scan blocks (196 for N=50000)

    // workspace carve
    char* p = (char*)d_ws;
    auto alloc = [&](size_t bytes) {
        char* r = p;
        p += (bytes + 255) & ~(size_t)255;
        return r;
    };
    float*    h       = (float*)alloc((size_t)N * HID * 4);
    float*    aggr    = (float*)alloc((size_t)N * HID * 4);
    float*    dist    = (float*)alloc((size_t)E * 4);
    int*      sj      = (int*)alloc((size_t)E * 4);
    float*    sdist   = (float*)alloc((size_t)E * 4);
    int*      counts  = (int*)alloc((size_t)N * 4);
    int*      row_ofs = (int*)alloc((size_t)(N + 1) * 4);
    int*      cursor  = (int*)alloc((size_t)N * 4);
    int*      pre     = (int*)alloc((size_t)N * 4);
    int*      bsums   = (int*)alloc((size_t)1024 * 4);
    float*    invdeg  = (float*)alloc((size_t)N * 4);
    float*    tabf    = (float*)alloc((size_t)NL * (BINS + 1) * HID * 4);
    __half2*  tabh    = (__half2*)alloc((size_t)NL * BINS * HID * 4);

    const int TB = 256;
    hipMemsetAsync(counts, 0, (size_t)N * 4, stream);
    hipMemsetAsync(d_out, 0, (size_t)out_size * sizeof(float), stream);

    k_dist<<<(E + TB - 1) / TB, TB, 0, stream>>>(ei, pos, dist, counts, E);
    k_scan1<<<NB, SB, 0, stream>>>(counts, pre, bsums, N);
    k_scan2<<<1, 1024, 0, stream>>>(bsums, NB);
    k_scan3<<<NB, SB, 0, stream>>>(pre, bsums, counts, row_ofs, cursor, N);
    k_scatter<<<(E + TB - 1) / TB, TB, 0, stream>>>(ei, dist, cursor, sj, sdist, E);
    int tot4 = N * 32;
    k_hinit<<<(tot4 + TB - 1) / TB, TB, 0, stream>>>(z, embed, h, tot4);
    k_invdeg<<<(N + TB - 1) / TB, TB, 0, stream>>>(counts, invdeg, N);
    k_tables<<<NL * (BINS + 1), HID, 0, stream>>>(fw1, fb1, fw2, fb2, tabf);
    k_pack<<<NL * BINS, HID, 0, stream>>>(tabf, tabh);

    int eblocks = (N + 3) / 4;      // 4 waves per 256-thread block, 1 wave per node
    int mblocks = (N + 63) / 64;

    for (int l = 0; l < NL; ++l) {
        k_edge<<<eblocks, TB, 0, stream>>>(row_ofs, sj, sdist, h,
                                           tabh + (size_t)l * BINS * HID,
                                           invdeg, aggr, N);
        k_mlp<false><<<mblocks, TB, 0, stream>>>(aggr,
                                                 uw1 + (size_t)l * HID * HID, ub1 + (size_t)l * HID,
                                                 uw2 + (size_t)l * HID * HID, ub2 + (size_t)l * HID,
                                                 h, N);
    }
    // output block: two ssp layers into aggr (scratch), then dot + segment sum
    k_mlp<true><<<mblocks, TB, 0, stream>>>(h, ow1, ob1, ow2, ob2, aggr, N);
    k_energy<<<eblocks, TB, 0, stream>>>(aggr, ow3, ob3, batch, (float*)d_out, N);
}

// Round 3
// 995.694 us; speedup vs baseline: 1.4811x; 1.3663x over previous
//
#include <hip/hip_runtime.h>
#include <hip/hip_fp16.h>
#include <math.h>

#define HID 128
#define RBF 32
#define NL 6
#define BINS 4096
#define DMAXF 5.0f
#define INV_STEP (4096.0f / 5.0f)
#define GAMMAF 32.0f
#define CSPACE (4.0f / 31.0f)   // linspace(0,4,32) spacing

typedef short short8 __attribute__((ext_vector_type(8)));
typedef short short4v __attribute__((ext_vector_type(4)));
typedef short short2v __attribute__((ext_vector_type(2)));
typedef float f32x4 __attribute__((ext_vector_type(4)));

__device__ __forceinline__ float sspf(float x) {
    // softplus(x) - 0.5, stable
    return fmaxf(x, 0.0f) + log1pf(expf(-fabsf(x))) - 0.5f;
}

__device__ __forceinline__ unsigned short f2bf(float x) {
    unsigned int u = __float_as_uint(x);
    unsigned int r = (u + 0x7fffu + ((u >> 16) & 1u)) >> 16;
    return (unsigned short)r;
}
__device__ __forceinline__ float bf2f(unsigned short b) {
    return __uint_as_float((unsigned int)b << 16);
}

// ---------- one-time preprocessing ----------

__global__ void k_dist(const int* __restrict__ ei, const float* __restrict__ pos,
                       float* __restrict__ dist, int* __restrict__ counts, int E_) {
    int e = blockIdx.x * blockDim.x + threadIdx.x;
    if (e >= E_) return;
    int i = ei[e], j = ei[E_ + e];
    float dx = pos[3 * i]     - pos[3 * j];
    float dy = pos[3 * i + 1] - pos[3 * j + 1];
    float dz = pos[3 * i + 2] - pos[3 * j + 2];
    dist[e] = sqrtf(dx * dx + dy * dy + dz * dz);
    atomicAdd(&counts[i], 1);
}

// hierarchical exclusive scan: 256-elem blocks -> block sums -> apply
#define SB 256
__global__ void k_scan1(const int* __restrict__ counts, int* __restrict__ pre,
                        int* __restrict__ bsums, int n) {
    __shared__ int s[SB];
    int tid = threadIdx.x;
    int g = blockIdx.x * SB + tid;
    int v = (g < n) ? counts[g] : 0;
    s[tid] = v;
    __syncthreads();
    for (int off = 1; off < SB; off <<= 1) {
        int t = (tid >= off) ? s[tid - off] : 0;
        __syncthreads();
        s[tid] += t;
        __syncthreads();
    }
    if (g < n) pre[g] = s[tid] - v;   // exclusive within block
    if (tid == SB - 1) bsums[blockIdx.x] = s[tid];
}

__global__ void k_scan2(int* __restrict__ bsums, int nb) {
    __shared__ int s[1024];
    int tid = threadIdx.x;
    int v = (tid < nb) ? bsums[tid] : 0;
    s[tid] = v;
    __syncthreads();
    for (int off = 1; off < 1024; off <<= 1) {
        int t = (tid >= off) ? s[tid - off] : 0;
        __syncthreads();
        s[tid] += t;
        __syncthreads();
    }
    if (tid < nb) bsums[tid] = s[tid] - v;  // exclusive block offsets
}

__global__ void k_scan3(const int* __restrict__ pre, const int* __restrict__ bsums,
                        const int* __restrict__ counts, int* __restrict__ row_ofs,
                        int* __restrict__ cursor, int n) {
    int g = blockIdx.x * SB + threadIdx.x;
    if (g >= n) return;
    int r = pre[g] + bsums[g >> 8];
    row_ofs[g] = r;
    cursor[g] = r;
    if (g == n - 1) row_ofs[n] = r + counts[g];
}

__global__ void k_scatter(const int* __restrict__ ei, const float* __restrict__ dist,
                          int* __restrict__ cursor, int* __restrict__ sj,
                          float* __restrict__ sdist, int E_) {
    int e = blockIdx.x * blockDim.x + threadIdx.x;
    if (e >= E_) return;
    int i = ei[e];
    int p = atomicAdd(&cursor[i], 1);
    sj[p] = ei[E_ + e];
    sdist[p] = dist[e];
}

// h (bf16) init from embedding
__global__ void k_hinit(const int* __restrict__ z, const float* __restrict__ embed,
                        unsigned short* __restrict__ h, int total4) {
    int idx = blockIdx.x * blockDim.x + threadIdx.x;
    if (idx >= total4) return;
    int node = idx >> 5, q = idx & 31;
    float4 v = ((const float4*)embed)[(size_t)z[node] * 32 + q];
    short4v o;
    o[0] = (short)f2bf(v.x); o[1] = (short)f2bf(v.y);
    o[2] = (short)f2bf(v.z); o[3] = (short)f2bf(v.w);
    *(short4v*)(h + (size_t)node * HID + q * 4) = o;
}

__global__ void k_invdeg(const int* __restrict__ counts, float* __restrict__ invdeg, int n) {
    int i = blockIdx.x * blockDim.x + threadIdx.x;
    if (i < n) invdeg[i] = 1.0f / fmaxf((float)counts[i], 1.0f);
}

// W(d) tables (fp32): for each layer, (BINS+1) rows of 128 — W = ssp(rbf@fw1+fb1)@fw2+fb2
__global__ void k_tables(const float* __restrict__ fw1, const float* __restrict__ fb1,
                         const float* __restrict__ fw2, const float* __restrict__ fb2,
                         float* __restrict__ tables) {
    int l = blockIdx.x / (BINS + 1);
    int bin = blockIdx.x % (BINS + 1);
    int c = threadIdx.x;
    __shared__ float rbf[RBF];
    __shared__ float P[HID];
    float d = (float)bin * (DMAXF / (float)BINS);
    if (c < RBF) {
        float dd = d - (float)c * CSPACE;
        rbf[c] = expf(-GAMMAF * dd * dd);
    }
    __syncthreads();
    float u = fb1[l * HID + c];
#pragma unroll 8
    for (int r = 0; r < RBF; ++r) u += rbf[r] * fw1[((size_t)l * RBF + r) * HID + c];
    P[c] = sspf(u);
    __syncthreads();
    float w = fb2[l * HID + c];
#pragma unroll 8
    for (int k = 0; k < HID; ++k) w += P[k] * fw2[((size_t)l * HID + k) * HID + c];
    tables[((size_t)l * (BINS + 1) + bin) * HID + c] = w;
}

// pack interleaved lerp endpoints: packed[l][b][c] = half2(W[b][c], W[b+1][c])
__global__ void k_pack(const float* __restrict__ tabf, __half2* __restrict__ packed) {
    int l = blockIdx.x / BINS, b = blockIdx.x % BINS;
    int c = threadIdx.x;
    const float* row = tabf + ((size_t)l * (BINS + 1) + b) * HID + c;
    packed[((size_t)l * BINS + b) * HID + c] = __floats2half2_rn(row[0], row[HID]);
}

// pack a 128x128 fp32 row-major weight matrix into MFMA B-fragment order (bf16).
// dst[((kt*8+nt)*64 + lane)*8 + j] = W[32*kt + 8*(lane>>4) + j][16*nt + (lane&15)]
__global__ void k_wpack(const float* __restrict__ W, unsigned short* __restrict__ dst) {
    int b = blockIdx.x;               // kt*8+nt, 0..31
    int kt = b >> 3, nt = b & 7;
    int lane = threadIdx.x;           // 64
    int m = lane & 15, g = lane >> 4;
    const float* src = W + (size_t)blockIdx.y * 16384;
    unsigned short* d = dst + (size_t)blockIdx.y * 16384 + ((size_t)b * 64 + lane) * 8;
#pragma unroll
    for (int j = 0; j < 8; ++j)
        d[j] = f2bf(src[(32 * kt + 8 * g + j) * 128 + 16 * nt + m]);
}

// ---------- per-layer edge pass: one wave per node, CSR, no atomics ----------
// h: bf16 [N][128]; table: half2-interleaved lerp pairs; aggr out: bf16
__global__ void k_edge(const int* __restrict__ row_ofs, const int* __restrict__ sj,
                       const float* __restrict__ sdist, const unsigned short* __restrict__ h,
                       const __half2* __restrict__ table, const float* __restrict__ invdeg,
                       unsigned short* __restrict__ aggr, int n) {
    int wv = (blockIdx.x * blockDim.x + threadIdx.x) >> 6;
    if (wv >= n) return;
    int lane = threadIdx.x & 63;
    int half = lane >> 5;   // two edges in flight per wave
    int sub = lane & 31;    // channel block: c = 4*sub .. 4*sub+3
    int beg = row_ofs[wv], end = row_ofs[wv + 1];
    float4 acc = make_float4(0.f, 0.f, 0.f, 0.f);
    const unsigned short* hB = h + 4 * sub;
    const __half2* tB = table + 4 * sub;
    for (int k = beg + half; k < end; k += 2) {
        int j = sj[k];
        float d = sdist[k];
        float t = fminf(d, DMAXF) * INV_STEP;
        int b = (int)t;
        b = b < (BINS - 1) ? b : (BINS - 1);
        float f = t - (float)b;
        short4v hj = *(const short4v*)(hB + (size_t)j * HID);
        float4 tw = *(const float4*)(tB + (size_t)b * HID);
        float2 p0 = __half22float2(*(__half2*)&tw.x);
        float2 p1 = __half22float2(*(__half2*)&tw.y);
        float2 p2 = __half22float2(*(__half2*)&tw.z);
        float2 p3 = __half22float2(*(__half2*)&tw.w);
        acc.x += bf2f((unsigned short)hj[0]) * (p0.x + f * (p0.y - p0.x));
        acc.y += bf2f((unsigned short)hj[1]) * (p1.x + f * (p1.y - p1.x));
        acc.z += bf2f((unsigned short)hj[2]) * (p2.x + f * (p2.y - p2.x));
        acc.w += bf2f((unsigned short)hj[3]) * (p3.x + f * (p3.y - p3.x));
    }
    acc.x += __shfl_xor(acc.x, 32);
    acc.y += __shfl_xor(acc.y, 32);
    acc.z += __shfl_xor(acc.z, 32);
    acc.w += __shfl_xor(acc.w, 32);
    if (half == 0) {
        float s = invdeg[wv];
        short4v o;
        o[0] = (short)f2bf(acc.x * s);
        o[1] = (short)f2bf(acc.y * s);
        o[2] = (short)f2bf(acc.z * s);
        o[3] = (short)f2bf(acc.w * s);
        *(short4v*)(aggr + (size_t)wv * HID + 4 * sub) = o;
    }
}

// ---------- fused 2-layer MLP via bf16 MFMA: Y = [ssp](ssp(X@W1+b1)@W2+b2) ----------
// X,Y: bf16 [M][128]; W1f,W2f: bf16 in MFMA B-frag order; b1,b2: fp32
template <bool SSP2>
__global__ __launch_bounds__(256) void k_mlp(const unsigned short* __restrict__ X,
                                             const unsigned short* __restrict__ W1f,
                                             const float* __restrict__ b1,
                                             const unsigned short* __restrict__ W2f,
                                             const float* __restrict__ b2,
                                             unsigned short* __restrict__ Y, int M) {
    __shared__ unsigned short T[64][136];   // row stride 272 B (16B-aligned, conflict-benign)
    const int tid = threadIdx.x;
    const int wave = tid >> 6, lane = tid & 63;
    const int m = lane & 15, g = lane >> 4;
    const int row0 = blockIdx.x * 64;
    const int c0 = wave * 32;               // this wave's output column base

    short8 zfrag;
#pragma unroll
    for (int q = 0; q < 8; ++q) zfrag[q] = 0;

    f32x4 acc[4][2];
#pragma unroll
    for (int rt = 0; rt < 4; ++rt)
#pragma unroll
        for (int t = 0; t < 2; ++t) acc[rt][t] = (f32x4){0.f, 0.f, 0.f, 0.f};

    // ---- phase 1: X @ W1 ----
#pragma unroll
    for (int kt = 0; kt < 4; ++kt) {
        short8 a[4];
#pragma unroll
        for (int rt = 0; rt < 4; ++rt) {
            int r = row0 + 16 * rt + m;
            a[rt] = (r < M) ? *(const short8*)(X + (size_t)r * HID + kt * 32 + g * 8) : zfrag;
        }
#pragma unroll
        for (int t = 0; t < 2; ++t) {
            int nt = (c0 >> 4) + t;
            short8 b = *(const short8*)(W1f + (((size_t)kt * 8 + nt) * 64 + lane) * 8);
#pragma unroll
            for (int rt = 0; rt < 4; ++rt)
                acc[rt][t] = __builtin_amdgcn_mfma_f32_16x16x32_bf16(a[rt], b, acc[rt][t], 0, 0, 0);
        }
    }
    // epilogue 1: +b1, ssp, to LDS as bf16 (C layout: col=lane&15, row=(lane>>4)*4+reg)
    {
        float bc0 = b1[c0 + m], bc1 = b1[c0 + 16 + m];
#pragma unroll
        for (int rt = 0; rt < 4; ++rt)
#pragma unroll
            for (int t = 0; t < 2; ++t) {
                int col = c0 + 16 * t + m;
                float bc = t ? bc1 : bc0;
#pragma unroll
                for (int reg = 0; reg < 4; ++reg)
                    T[16 * rt + 4 * g + reg][col] = f2bf(sspf(acc[rt][t][reg] + bc));
            }
    }
    __syncthreads();

    // ---- phase 2: T @ W2 ----
#pragma unroll
    for (int rt = 0; rt < 4; ++rt)
#pragma unroll
        for (int t = 0; t < 2; ++t) acc[rt][t] = (f32x4){0.f, 0.f, 0.f, 0.f};

#pragma unroll
    for (int kt = 0; kt < 4; ++kt) {
        short8 a[4];
#pragma unroll
        for (int rt = 0; rt < 4; ++rt)
            a[rt] = *(const short8*)&T[16 * rt + m][kt * 32 + g * 8];
#pragma unroll
        for (int t = 0; t < 2; ++t) {
            int nt = (c0 >> 4) + t;
            short8 b = *(const short8*)(W2f + (((size_t)kt * 8 + nt) * 64 + lane) * 8);
#pragma unroll
            for (int rt = 0; rt < 4; ++rt)
                acc[rt][t] = __builtin_amdgcn_mfma_f32_16x16x32_bf16(a[rt], b, acc[rt][t], 0, 0, 0);
        }
    }
    __syncthreads();   // all T reads done before overwrite
    // epilogue 2: +b2 (, ssp), back to LDS
    {
        float bc0 = b2[c0 + m], bc1 = b2[c0 + 16 + m];
#pragma unroll
        for (int rt = 0; rt < 4; ++rt)
#pragma unroll
            for (int t = 0; t < 2; ++t) {
                int col = c0 + 16 * t + m;
                float bc = t ? bc1 : bc0;
#pragma unroll
                for (int reg = 0; reg < 4; ++reg) {
                    float v = acc[rt][t][reg] + bc;
                    if (SSP2) v = sspf(v);
                    T[16 * rt + 4 * g + reg][col] = f2bf(v);
                }
            }
    }
    __syncthreads();
    // coalesced bf16x8 global store
    for (int it = tid; it < 1024; it += 256) {
        int row = it >> 4, cc = (it & 15) * 8;
        int r = row0 + row;
        if (r < M)
            *(short8*)(Y + (size_t)r * HID + cc) = *(const short8*)&T[row][cc];
    }
}

// ---------- output: e_atom = E2 @ ow3 + ob3, summed per graph ----------
__global__ void k_energy(const unsigned short* __restrict__ E2, const float* __restrict__ ow3,
                         const float* __restrict__ ob3, const int* __restrict__ batch,
                         float* __restrict__ out, int n) {
    int wv = (blockIdx.x * blockDim.x + threadIdx.x) >> 6;
    if (wv >= n) return;
    int lane = threadIdx.x & 63;
    short2v v = *(const short2v*)(E2 + (size_t)wv * HID + 2 * lane);
    float2 w = *(const float2*)(ow3 + 2 * lane);
    float s = bf2f((unsigned short)v[0]) * w.x + bf2f((unsigned short)v[1]) * w.y;
#pragma unroll
    for (int o = 32; o > 0; o >>= 1) s += __shfl_xor(s, o);
    if (lane == 0) atomicAdd(&out[batch[wv]], s + ob3[0]);
}

extern "C" void kernel_launch(void* const* d_in, const int* in_sizes, int n_in,
                              void* d_out, int out_size, void* d_ws, size_t ws_size,
                              hipStream_t stream) {
    const int*   z     = (const int*)d_in[0];
    const float* pos   = (const float*)d_in[1];
    const int*   ei    = (const int*)d_in[2];
    const int*   batch = (const int*)d_in[3];
    const float* embed = (const float*)d_in[4];
    const float* fw1   = (const float*)d_in[5];
    const float* fb1   = (const float*)d_in[6];
    const float* fw2   = (const float*)d_in[7];
    const float* fb2   = (const float*)d_in[8];
    const float* uw1   = (const float*)d_in[9];
    const float* ub1   = (const float*)d_in[10];
    const float* uw2   = (const float*)d_in[11];
    const float* ub2   = (const float*)d_in[12];
    const float* ow1   = (const float*)d_in[13];
    const float* ob1   = (const float*)d_in[14];
    const float* ow2   = (const float*)d_in[15];
    const float* ob2   = (const float*)d_in[16];
    const float* ow3   = (const float*)d_in[17];
    const float* ob3   = (const float*)d_in[18];

    const int N = in_sizes[0];
    const int E = in_sizes[2] / 2;
    const int NB = (N + SB - 1) / SB;

    // workspace carve
    char* p = (char*)d_ws;
    auto alloc = [&](size_t bytes) {
        char* r = p;
        p += (bytes + 255) & ~(size_t)255;
        return r;
    };
    unsigned short* h       = (unsigned short*)alloc((size_t)(N + 64) * HID * 2);
    unsigned short* aggr    = (unsigned short*)alloc((size_t)(N + 64) * HID * 2);
    float*    dist    = (float*)alloc((size_t)E * 4);
    int*      sj      = (int*)alloc((size_t)E * 4);
    float*    sdist   = (float*)alloc((size_t)E * 4);
    int*      counts  = (int*)alloc((size_t)N * 4);
    int*      row_ofs = (int*)alloc((size_t)(N + 1) * 4);
    int*      cursor  = (int*)alloc((size_t)N * 4);
    int*      pre     = (int*)alloc((size_t)N * 4);
    int*      bsums   = (int*)alloc((size_t)1024 * 4);
    float*    invdeg  = (float*)alloc((size_t)N * 4);
    float*    tabf    = (float*)alloc((size_t)NL * (BINS + 1) * HID * 4);
    __half2*  tabh    = (__half2*)alloc((size_t)NL * BINS * HID * 4);
    unsigned short* uw1b = (unsigned short*)alloc((size_t)NL * 16384 * 2);
    unsigned short* uw2b = (unsigned short*)alloc((size_t)NL * 16384 * 2);
    unsigned short* ow1b = (unsigned short*)alloc((size_t)16384 * 2);
    unsigned short* ow2b = (unsigned short*)alloc((size_t)16384 * 2);

    const int TB = 256;
    hipMemsetAsync(counts, 0, (size_t)N * 4, stream);
    hipMemsetAsync(d_out, 0, (size_t)out_size * sizeof(float), stream);

    k_dist<<<(E + TB - 1) / TB, TB, 0, stream>>>(ei, pos, dist, counts, E);
    k_scan1<<<NB, SB, 0, stream>>>(counts, pre, bsums, N);
    k_scan2<<<1, 1024, 0, stream>>>(bsums, NB);
    k_scan3<<<NB, SB, 0, stream>>>(pre, bsums, counts, row_ofs, cursor, N);
    k_scatter<<<(E + TB - 1) / TB, TB, 0, stream>>>(ei, dist, cursor, sj, sdist, E);
    int tot4 = N * 32;
    k_hinit<<<(tot4 + TB - 1) / TB, TB, 0, stream>>>(z, embed, h, tot4);
    k_invdeg<<<(N + TB - 1) / TB, TB, 0, stream>>>(counts, invdeg, N);
    k_tables<<<NL * (BINS + 1), HID, 0, stream>>>(fw1, fb1, fw2, fb2, tabf);
    k_pack<<<NL * BINS, HID, 0, stream>>>(tabf, tabh);
    k_wpack<<<dim3(32, NL), 64, 0, stream>>>(uw1, uw1b);
    k_wpack<<<dim3(32, NL), 64, 0, stream>>>(uw2, uw2b);
    k_wpack<<<dim3(32, 1), 64, 0, stream>>>(ow1, ow1b);
    k_wpack<<<dim3(32, 1), 64, 0, stream>>>(ow2, ow2b);

    int eblocks = (N + 3) / 4;      // 4 waves per 256-thread block, 1 wave per node
    int mblocks = (N + 63) / 64;

    for (int l = 0; l < NL; ++l) {
        k_edge<<<eblocks, TB, 0, stream>>>(row_ofs, sj, sdist, h,
                                           tabh + (size_t)l * BINS * HID,
                                           invdeg, aggr, N);
        k_mlp<false><<<mblocks, TB, 0, stream>>>(aggr,
                                                 uw1b + (size_t)l * 16384, ub1 + (size_t)l * HID,
                                                 uw2b + (size_t)l * 16384, ub2 + (size_t)l * HID,
                                                 h, N);
    }
    // output block: two ssp layers into aggr (scratch), then dot + segment sum
    k_mlp<true><<<mblocks, TB, 0, stream>>>(h, ow1b, ob1, ow2b, ob2, aggr, N);
    k_energy<<<eblocks, TB, 0, stream>>>(aggr, ow3, ob3, batch, (float*)d_out, N);
}

// Round 4
// 809.395 us; speedup vs baseline: 1.8220x; 1.2302x over previous
//
#include <hip/hip_runtime.h>
#include <math.h>

#define HID 128
#define RBF 32
#define NL 6
#define BINS 4096
#define DMAXF 5.0f
#define INV_STEP (4096.0f / 5.0f)
#define GAMMAF 32.0f
#define CSPACE (4.0f / 31.0f)   // linspace(0,4,32) spacing

typedef _Float16 half8v __attribute__((ext_vector_type(8)));
typedef _Float16 half4v __attribute__((ext_vector_type(4)));
typedef float f32x4 __attribute__((ext_vector_type(4)));

__device__ __forceinline__ float sspf(float x) {
    // softplus(x) - 0.5, stable
    return fmaxf(x, 0.0f) + log1pf(expf(-fabsf(x))) - 0.5f;
}

// ---------- one-time preprocessing ----------

__global__ void k_count(const int* __restrict__ ei, int* __restrict__ counts, int E_) {
    int e = blockIdx.x * blockDim.x + threadIdx.x;
    if (e >= E_) return;
    atomicAdd(&counts[ei[e]], 1);
}

// hierarchical exclusive scan: 256-elem blocks -> block sums -> apply
#define SB 256
__global__ void k_scan1(const int* __restrict__ counts, int* __restrict__ pre,
                        int* __restrict__ bsums, int n) {
    __shared__ int s[SB];
    int tid = threadIdx.x;
    int g = blockIdx.x * SB + tid;
    int v = (g < n) ? counts[g] : 0;
    s[tid] = v;
    __syncthreads();
    for (int off = 1; off < SB; off <<= 1) {
        int t = (tid >= off) ? s[tid - off] : 0;
        __syncthreads();
        s[tid] += t;
        __syncthreads();
    }
    if (g < n) pre[g] = s[tid] - v;   // exclusive within block
    if (tid == SB - 1) bsums[blockIdx.x] = s[tid];
}

__global__ void k_scan2(int* __restrict__ bsums, int nb) {
    __shared__ int s[1024];
    int tid = threadIdx.x;
    int v = (tid < nb) ? bsums[tid] : 0;
    s[tid] = v;
    __syncthreads();
    for (int off = 1; off < 1024; off <<= 1) {
        int t = (tid >= off) ? s[tid - off] : 0;
        __syncthreads();
        s[tid] += t;
        __syncthreads();
    }
    if (tid < nb) bsums[tid] = s[tid] - v;  // exclusive block offsets
}

__global__ void k_scan3(const int* __restrict__ pre, const int* __restrict__ bsums,
                        const int* __restrict__ counts, int* __restrict__ row_ofs,
                        int* __restrict__ cursor, int n) {
    int g = blockIdx.x * SB + threadIdx.x;
    if (g >= n) return;
    int r = pre[g] + bsums[g >> 8];
    row_ofs[g] = r;
    cursor[g] = r;
    if (g == n - 1) row_ofs[n] = r + counts[g];
}

// compute dist, quantize to bin, pack (j | bin<<17) into CSR order
__global__ void k_scatter(const int* __restrict__ ei, const float* __restrict__ pos,
                          int* __restrict__ cursor, unsigned int* __restrict__ epk, int E_) {
    int e = blockIdx.x * blockDim.x + threadIdx.x;
    if (e >= E_) return;
    int i = ei[e], j = ei[E_ + e];
    float dx = pos[3 * i]     - pos[3 * j];
    float dy = pos[3 * i + 1] - pos[3 * j + 1];
    float dz = pos[3 * i + 2] - pos[3 * j + 2];
    float d = sqrtf(dx * dx + dy * dy + dz * dz);
    float t = fminf(d, DMAXF) * INV_STEP;
    unsigned int b = (unsigned int)(t + 0.5f);   // nearest bin, 0..4096
    int p = atomicAdd(&cursor[i], 1);
    epk[p] = (unsigned int)j | (b << 17);
}

// h (fp16) init from embedding
__global__ void k_hinit(const int* __restrict__ z, const float* __restrict__ embed,
                        _Float16* __restrict__ h, int total4) {
    int idx = blockIdx.x * blockDim.x + threadIdx.x;
    if (idx >= total4) return;
    int node = idx >> 5, q = idx & 31;
    float4 v = ((const float4*)embed)[(size_t)z[node] * 32 + q];
    half4v o;
    o[0] = (_Float16)v.x; o[1] = (_Float16)v.y;
    o[2] = (_Float16)v.z; o[3] = (_Float16)v.w;
    *(half4v*)(h + (size_t)node * HID + q * 4) = o;
}

__global__ void k_invdeg(const int* __restrict__ counts, float* __restrict__ invdeg, int n) {
    int i = blockIdx.x * blockDim.x + threadIdx.x;
    if (i < n) invdeg[i] = 1.0f / fmaxf((float)counts[i], 1.0f);
}

// W(d) tables (fp16, nearest-bin): per layer, (BINS+1) rows of 128
__global__ void k_tables(const float* __restrict__ fw1, const float* __restrict__ fb1,
                         const float* __restrict__ fw2, const float* __restrict__ fb2,
                         _Float16* __restrict__ tables) {
    int l = blockIdx.x / (BINS + 1);
    int bin = blockIdx.x % (BINS + 1);
    int c = threadIdx.x;
    __shared__ float rbf[RBF];
    __shared__ float P[HID];
    float d = (float)bin * (DMAXF / (float)BINS);
    if (c < RBF) {
        float dd = d - (float)c * CSPACE;
        rbf[c] = expf(-GAMMAF * dd * dd);
    }
    __syncthreads();
    float u = fb1[l * HID + c];
#pragma unroll 8
    for (int r = 0; r < RBF; ++r) u += rbf[r] * fw1[((size_t)l * RBF + r) * HID + c];
    P[c] = sspf(u);
    __syncthreads();
    float w = fb2[l * HID + c];
#pragma unroll 8
    for (int k = 0; k < HID; ++k) w += P[k] * fw2[((size_t)l * HID + k) * HID + c];
    tables[((size_t)l * (BINS + 1) + bin) * HID + c] = (_Float16)w;
}

// pack a 128x128 fp32 row-major weight matrix into MFMA B-fragment order (fp16).
// dst[((kt*8+nt)*64 + lane)*8 + j] = W[32*kt + 8*(lane>>4) + j][16*nt + (lane&15)]
__global__ void k_wpack(const float* __restrict__ W, _Float16* __restrict__ dst) {
    int b = blockIdx.x;               // kt*8+nt, 0..31
    int kt = b >> 3, nt = b & 7;
    int lane = threadIdx.x;           // 64
    int m = lane & 15, g = lane >> 4;
    const float* src = W + (size_t)blockIdx.y * 16384;
    _Float16* d = dst + (size_t)blockIdx.y * 16384 + ((size_t)b * 64 + lane) * 8;
#pragma unroll
    for (int j = 0; j < 8; ++j)
        d[j] = (_Float16)src[(32 * kt + 8 * g + j) * 128 + 16 * nt + m];
}

// ---------- per-layer edge pass: one wave per node, 4 edges in flight ----------
// h: fp16 [N][128]; table: fp16 nearest-bin rows; aggr out: fp16
__global__ void k_edge(const int* __restrict__ row_ofs, const unsigned int* __restrict__ epk,
                       const _Float16* __restrict__ h, const _Float16* __restrict__ table,
                       const float* __restrict__ invdeg, _Float16* __restrict__ aggr, int n) {
    int wv = (blockIdx.x * blockDim.x + threadIdx.x) >> 6;
    if (wv >= n) return;
    int lane = threadIdx.x & 63;
    int quarter = lane >> 4;   // 4 edges in flight per wave
    int sub = lane & 15;       // channel block: c = 8*sub .. 8*sub+7
    int beg = row_ofs[wv], end = row_ofs[wv + 1];
    float acc[8];
#pragma unroll
    for (int q = 0; q < 8; ++q) acc[q] = 0.f;
    const _Float16* hB = h + 8 * sub;
    const _Float16* tB = table + 8 * sub;
    for (int k = beg + quarter; k < end; k += 4) {
        unsigned int pk = epk[k];
        int j = pk & 0x1FFFF;
        int b = pk >> 17;
        half8v hj = *(const half8v*)(hB + (size_t)j * HID);
        half8v tw = *(const half8v*)(tB + (size_t)b * HID);
#pragma unroll
        for (int q = 0; q < 8; ++q) acc[q] += (float)hj[q] * (float)tw[q];
    }
#pragma unroll
    for (int q = 0; q < 8; ++q) {
        acc[q] += __shfl_xor(acc[q], 32);
        acc[q] += __shfl_xor(acc[q], 16);
    }
    if (quarter == 0) {
        float s = invdeg[wv];
        half8v o;
#pragma unroll
        for (int q = 0; q < 8; ++q) o[q] = (_Float16)(acc[q] * s);
        *(half8v*)(aggr + (size_t)wv * HID + 8 * sub) = o;
    }
}

// ---------- fused 2-layer MLP via fp16 MFMA ----------
// MODE 0: Y = ssp(X@W1+b1)@W2+b2, stored fp16
// MODE 1: e = ssp(ssp(X@W1+b1)@W2+b2) @ ow3 + ob3 per row, segment-summed into out
template <int MODE>
__global__ __launch_bounds__(256) void k_mlp(const _Float16* __restrict__ X,
                                             const _Float16* __restrict__ W1f,
                                             const float* __restrict__ b1,
                                             const _Float16* __restrict__ W2f,
                                             const float* __restrict__ b2,
                                             _Float16* __restrict__ Y,
                                             const float* __restrict__ ow3,
                                             const float* __restrict__ ob3,
                                             const int* __restrict__ batch,
                                             float* __restrict__ out, int M) {
    __shared__ _Float16 T[64][136];
    const int tid = threadIdx.x;
    const int wave = tid >> 6, lane = tid & 63;
    const int m = lane & 15, g = lane >> 4;
    const int row0 = blockIdx.x * 64;
    const int c0 = wave * 32;               // this wave's output column base

    half8v zfrag;
#pragma unroll
    for (int q = 0; q < 8; ++q) zfrag[q] = (_Float16)0.f;

    f32x4 acc[4][2];
#pragma unroll
    for (int rt = 0; rt < 4; ++rt)
#pragma unroll
        for (int t = 0; t < 2; ++t) acc[rt][t] = (f32x4){0.f, 0.f, 0.f, 0.f};

    // ---- phase 1: X @ W1 ----
#pragma unroll
    for (int kt = 0; kt < 4; ++kt) {
        half8v a[4];
#pragma unroll
        for (int rt = 0; rt < 4; ++rt) {
            int r = row0 + 16 * rt + m;
            a[rt] = (r < M) ? *(const half8v*)(X + (size_t)r * HID + kt * 32 + g * 8) : zfrag;
        }
#pragma unroll
        for (int t = 0; t < 2; ++t) {
            int nt = (c0 >> 4) + t;
            half8v b = *(const half8v*)(W1f + (((size_t)kt * 8 + nt) * 64 + lane) * 8);
#pragma unroll
            for (int rt = 0; rt < 4; ++rt)
                acc[rt][t] = __builtin_amdgcn_mfma_f32_16x16x32_f16(a[rt], b, acc[rt][t], 0, 0, 0);
        }
    }
    // epilogue 1: +b1, ssp, to LDS fp16 (C layout: col=lane&15, row=(lane>>4)*4+reg)
    {
        float bc0 = b1[c0 + m], bc1 = b1[c0 + 16 + m];
#pragma unroll
        for (int rt = 0; rt < 4; ++rt)
#pragma unroll
            for (int t = 0; t < 2; ++t) {
                int col = c0 + 16 * t + m;
                float bc = t ? bc1 : bc0;
#pragma unroll
                for (int reg = 0; reg < 4; ++reg)
                    T[16 * rt + 4 * g + reg][col] = (_Float16)sspf(acc[rt][t][reg] + bc);
            }
    }
    __syncthreads();

    // ---- phase 2: T @ W2 ----
#pragma unroll
    for (int rt = 0; rt < 4; ++rt)
#pragma unroll
        for (int t = 0; t < 2; ++t) acc[rt][t] = (f32x4){0.f, 0.f, 0.f, 0.f};

#pragma unroll
    for (int kt = 0; kt < 4; ++kt) {
        half8v a[4];
#pragma unroll
        for (int rt = 0; rt < 4; ++rt)
            a[rt] = *(const half8v*)&T[16 * rt + m][kt * 32 + g * 8];
#pragma unroll
        for (int t = 0; t < 2; ++t) {
            int nt = (c0 >> 4) + t;
            half8v b = *(const half8v*)(W2f + (((size_t)kt * 8 + nt) * 64 + lane) * 8);
#pragma unroll
            for (int rt = 0; rt < 4; ++rt)
                acc[rt][t] = __builtin_amdgcn_mfma_f32_16x16x32_f16(a[rt], b, acc[rt][t], 0, 0, 0);
        }
    }

    if (MODE == 0) {
        __syncthreads();   // all T reads done before overwrite
        float bc0 = b2[c0 + m], bc1 = b2[c0 + 16 + m];
#pragma unroll
        for (int rt = 0; rt < 4; ++rt)
#pragma unroll
            for (int t = 0; t < 2; ++t) {
                int col = c0 + 16 * t + m;
                float bc = t ? bc1 : bc0;
#pragma unroll
                for (int reg = 0; reg < 4; ++reg)
                    T[16 * rt + 4 * g + reg][col] = (_Float16)(acc[rt][t][reg] + bc);
            }
        __syncthreads();
        for (int it = tid; it < 1024; it += 256) {
            int row = it >> 4, cc = (it & 15) * 8;
            int r = row0 + row;
            if (r < M)
                *(half8v*)(Y + (size_t)r * HID + cc) = *(const half8v*)&T[row][cc];
        }
    } else {
        // fused energy: e_row = ssp(acc+b2) . ow3, fp32 throughout
        __shared__ float ea[4][64];
        __shared__ float ev[64];
        __shared__ int   bv[64];
        float bc0 = b2[c0 + m], bc1 = b2[c0 + 16 + m];
        float w0 = ow3[c0 + m], w1 = ow3[c0 + 16 + m];
#pragma unroll
        for (int rt = 0; rt < 4; ++rt) {
#pragma unroll
            for (int reg = 0; reg < 4; ++reg) {
                float p = sspf(acc[rt][0][reg] + bc0) * w0
                        + sspf(acc[rt][1][reg] + bc1) * w1;
                p += __shfl_xor(p, 1);
                p += __shfl_xor(p, 2);
                p += __shfl_xor(p, 4);
                p += __shfl_xor(p, 8);
                if (m == 0) ea[wave][16 * rt + 4 * g + reg] = p;
            }
        }
        __syncthreads();
        if (tid < 64) {
            int r = tid, row = row0 + r;
            float e = ea[0][r] + ea[1][r] + ea[2][r] + ea[3][r] + ob3[0];
            int bid = (row < M) ? batch[row] : -1;
            ev[r] = (row < M) ? e : 0.f;
            bv[r] = bid;
        }
        __syncthreads();
        if (tid < 64) {
            int r = tid, bid = bv[r];
            if (bid >= 0 && (r == 0 || bv[r - 1] != bid)) {
                float s = 0.f;
                for (int k = r; k < 64 && bv[k] == bid; ++k) s += ev[k];
                atomicAdd(&out[bid], s);
            }
        }
    }
}

extern "C" void kernel_launch(void* const* d_in, const int* in_sizes, int n_in,
                              void* d_out, int out_size, void* d_ws, size_t ws_size,
                              hipStream_t stream) {
    const int*   z     = (const int*)d_in[0];
    const float* pos   = (const float*)d_in[1];
    const int*   ei    = (const int*)d_in[2];
    const int*   batch = (const int*)d_in[3];
    const float* embed = (const float*)d_in[4];
    const float* fw1   = (const float*)d_in[5];
    const float* fb1   = (const float*)d_in[6];
    const float* fw2   = (const float*)d_in[7];
    const float* fb2   = (const float*)d_in[8];
    const float* uw1   = (const float*)d_in[9];
    const float* ub1   = (const float*)d_in[10];
    const float* uw2   = (const float*)d_in[11];
    const float* ub2   = (const float*)d_in[12];
    const float* ow1   = (const float*)d_in[13];
    const float* ob1   = (const float*)d_in[14];
    const float* ow2   = (const float*)d_in[15];
    const float* ob2   = (const float*)d_in[16];
    const float* ow3   = (const float*)d_in[17];
    const float* ob3   = (const float*)d_in[18];

    const int N = in_sizes[0];
    const int E = in_sizes[2] / 2;
    const int NB = (N + SB - 1) / SB;

    // workspace carve
    char* p = (char*)d_ws;
    auto alloc = [&](size_t bytes) {
        char* r = p;
        p += (bytes + 255) & ~(size_t)255;
        return r;
    };
    _Float16* h       = (_Float16*)alloc((size_t)(N + 64) * HID * 2);
    _Float16* aggr    = (_Float16*)alloc((size_t)(N + 64) * HID * 2);
    unsigned int* epk = (unsigned int*)alloc((size_t)E * 4);
    int*      counts  = (int*)alloc((size_t)N * 4);
    int*      row_ofs = (int*)alloc((size_t)(N + 1) * 4);
    int*      cursor  = (int*)alloc((size_t)N * 4);
    int*      pre     = (int*)alloc((size_t)N * 4);
    int*      bsums   = (int*)alloc((size_t)1024 * 4);
    float*    invdeg  = (float*)alloc((size_t)N * 4);
    _Float16* tab16   = (_Float16*)alloc((size_t)NL * (BINS + 1) * HID * 2);
    _Float16* uw1b    = (_Float16*)alloc((size_t)NL * 16384 * 2);
    _Float16* uw2b    = (_Float16*)alloc((size_t)NL * 16384 * 2);
    _Float16* ow1b    = (_Float16*)alloc((size_t)16384 * 2);
    _Float16* ow2b    = (_Float16*)alloc((size_t)16384 * 2);

    const int TB = 256;
    hipMemsetAsync(counts, 0, (size_t)N * 4, stream);
    hipMemsetAsync(d_out, 0, (size_t)out_size * sizeof(float), stream);

    k_count<<<(E + TB - 1) / TB, TB, 0, stream>>>(ei, counts, E);
    k_scan1<<<NB, SB, 0, stream>>>(counts, pre, bsums, N);
    k_scan2<<<1, 1024, 0, stream>>>(bsums, NB);
    k_scan3<<<NB, SB, 0, stream>>>(pre, bsums, counts, row_ofs, cursor, N);
    k_scatter<<<(E + TB - 1) / TB, TB, 0, stream>>>(ei, pos, cursor, epk, E);
    int tot4 = N * 32;
    k_hinit<<<(tot4 + TB - 1) / TB, TB, 0, stream>>>(z, embed, h, tot4);
    k_invdeg<<<(N + TB - 1) / TB, TB, 0, stream>>>(counts, invdeg, N);
    k_tables<<<NL * (BINS + 1), HID, 0, stream>>>(fw1, fb1, fw2, fb2, tab16);
    k_wpack<<<dim3(32, NL), 64, 0, stream>>>(uw1, uw1b);
    k_wpack<<<dim3(32, NL), 64, 0, stream>>>(uw2, uw2b);
    k_wpack<<<dim3(32, 1), 64, 0, stream>>>(ow1, ow1b);
    k_wpack<<<dim3(32, 1), 64, 0, stream>>>(ow2, ow2b);

    int eblocks = (N + 3) / 4;      // 4 waves per 256-thread block, 1 wave per node
    int mblocks = (N + 63) / 64;

    for (int l = 0; l < NL; ++l) {
        k_edge<<<eblocks, TB, 0, stream>>>(row_ofs, epk, h,
                                           tab16 + (size_t)l * (BINS + 1) * HID,
                                           invdeg, aggr, N);
        k_mlp<0><<<mblocks, TB, 0, stream>>>(aggr,
                                             uw1b + (size_t)l * 16384, ub1 + (size_t)l * HID,
                                             uw2b + (size_t)l * 16384, ub2 + (size_t)l * HID,
                                             h, nullptr, nullptr, nullptr, nullptr, N);
    }
    // output block fused with energy reduction
    k_mlp<1><<<mblocks, TB, 0, stream>>>(h, ow1b, ob1, ow2b, ob2, nullptr,
                                         ow3, ob3, batch, (float*)d_out, N);
}

// Round 5
// 725.364 us; speedup vs baseline: 2.0331x; 1.1158x over previous
//
#include <hip/hip_runtime.h>
#include <math.h>

#define HID 128
#define RBF 32
#define NL 6
#define BINS 4096
#define DMAXF 5.0f
#define INV_STEP (4096.0f / 5.0f)
#define GAMMAF 32.0f
#define CSPACE (4.0f / 31.0f)   // linspace(0,4,32) spacing

typedef _Float16 half8v __attribute__((ext_vector_type(8)));
typedef _Float16 half4v __attribute__((ext_vector_type(4)));
typedef float f32x4 __attribute__((ext_vector_type(4)));

__device__ __forceinline__ float sspf(float x) {
    // softplus(x) - 0.5, stable
    return fmaxf(x, 0.0f) + log1pf(expf(-fabsf(x))) - 0.5f;
}

// ---------- one-time preprocessing ----------

__global__ void k_count(const int* __restrict__ ei, int* __restrict__ counts, int E_) {
    int e = blockIdx.x * blockDim.x + threadIdx.x;
    if (e >= E_) return;
    atomicAdd(&counts[ei[e]], 1);
}

// hierarchical exclusive scan: 256-elem blocks -> block sums -> apply
#define SB 256
__global__ void k_scan1(const int* __restrict__ counts, int* __restrict__ pre,
                        int* __restrict__ bsums, int n) {
    __shared__ int s[SB];
    int tid = threadIdx.x;
    int g = blockIdx.x * SB + tid;
    int v = (g < n) ? counts[g] : 0;
    s[tid] = v;
    __syncthreads();
    for (int off = 1; off < SB; off <<= 1) {
        int t = (tid >= off) ? s[tid - off] : 0;
        __syncthreads();
        s[tid] += t;
        __syncthreads();
    }
    if (g < n) pre[g] = s[tid] - v;   // exclusive within block
    if (tid == SB - 1) bsums[blockIdx.x] = s[tid];
}

__global__ void k_scan2(int* __restrict__ bsums, int nb) {
    __shared__ int s[1024];
    int tid = threadIdx.x;
    int v = (tid < nb) ? bsums[tid] : 0;
    s[tid] = v;
    __syncthreads();
    for (int off = 1; off < 1024; off <<= 1) {
        int t = (tid >= off) ? s[tid - off] : 0;
        __syncthreads();
        s[tid] += t;
        __syncthreads();
    }
    if (tid < nb) bsums[tid] = s[tid] - v;  // exclusive block offsets
}

__global__ void k_scan3(const int* __restrict__ pre, const int* __restrict__ bsums,
                        const int* __restrict__ counts, int* __restrict__ row_ofs,
                        int* __restrict__ cursor, int n) {
    int g = blockIdx.x * SB + threadIdx.x;
    if (g >= n) return;
    int r = pre[g] + bsums[g >> 8];
    row_ofs[g] = r;
    cursor[g] = r;
    if (g == n - 1) row_ofs[n] = r + counts[g];
}

// compute dist, quantize to bin, pack (j | bin<<17) into CSR order
__global__ void k_scatter(const int* __restrict__ ei, const float* __restrict__ pos,
                          int* __restrict__ cursor, unsigned int* __restrict__ epk, int E_) {
    int e = blockIdx.x * blockDim.x + threadIdx.x;
    if (e >= E_) return;
    int i = ei[e], j = ei[E_ + e];
    float dx = pos[3 * i]     - pos[3 * j];
    float dy = pos[3 * i + 1] - pos[3 * j + 1];
    float dz = pos[3 * i + 2] - pos[3 * j + 2];
    float d = sqrtf(dx * dx + dy * dy + dz * dz);
    float t = fminf(d, DMAXF) * INV_STEP;
    unsigned int b = (unsigned int)(t + 0.5f);   // nearest bin, 0..4096
    int p = atomicAdd(&cursor[i], 1);
    epk[p] = (unsigned int)j | (b << 17);
}

// h (fp16) init from embedding
__global__ void k_hinit(const int* __restrict__ z, const float* __restrict__ embed,
                        _Float16* __restrict__ h, int total4) {
    int idx = blockIdx.x * blockDim.x + threadIdx.x;
    if (idx >= total4) return;
    int node = idx >> 5, q = idx & 31;
    float4 v = ((const float4*)embed)[(size_t)z[node] * 32 + q];
    half4v o;
    o[0] = (_Float16)v.x; o[1] = (_Float16)v.y;
    o[2] = (_Float16)v.z; o[3] = (_Float16)v.w;
    *(half4v*)(h + (size_t)node * HID + q * 4) = o;
}

__global__ void k_invdeg(const int* __restrict__ counts, float* __restrict__ invdeg, int n) {
    int i = blockIdx.x * blockDim.x + threadIdx.x;
    if (i < n) invdeg[i] = 1.0f / fmaxf((float)counts[i], 1.0f);
}

// pack a 128x128 fp32 row-major weight matrix into MFMA B-fragment order (fp16).
// dst[((kt*8+nt)*64 + lane)*8 + j] = W[32*kt + 8*(lane>>4) + j][16*nt + (lane&15)]
__global__ void k_wpack(const float* __restrict__ W, _Float16* __restrict__ dst) {
    int b = blockIdx.x;               // kt*8+nt, 0..31
    int kt = b >> 3, nt = b & 7;
    int lane = threadIdx.x;           // 64
    int m = lane & 15, g = lane >> 4;
    const float* src = W + (size_t)blockIdx.y * 16384;
    _Float16* d = dst + (size_t)blockIdx.y * 16384 + ((size_t)b * 64 + lane) * 8;
#pragma unroll
    for (int j = 0; j < 8; ++j)
        d[j] = (_Float16)src[(32 * kt + 8 * g + j) * 128 + 16 * nt + m];
}

// pack a 32x128 fp32 weight (fw1 layer) into single-kt B-fragment order (fp16)
__global__ void k_wpack32(const float* __restrict__ W, _Float16* __restrict__ dst) {
    int nt = blockIdx.x;              // 0..7
    int lane = threadIdx.x;           // 64
    int m = lane & 15, g = lane >> 4;
    const float* src = W + (size_t)blockIdx.y * RBF * HID;
    _Float16* d = dst + (size_t)blockIdx.y * RBF * HID + ((size_t)nt * 64 + lane) * 8;
#pragma unroll
    for (int j = 0; j < 8; ++j)
        d[j] = (_Float16)src[(8 * g + j) * 128 + 16 * nt + m];
}

// ---------- MFMA table build: tables[l][bin][c] = ssp(rbf@fw1+fb1)@fw2+fb2 ----------
// grid (ceil((BINS+1)/64), NL), 256 threads; w1f: K=32 frag-packed, w2f: 128x128 frag-packed
__global__ __launch_bounds__(256) void k_tabmm(const _Float16* __restrict__ w1f,
                                               const float* __restrict__ fb1,
                                               const _Float16* __restrict__ w2f,
                                               const float* __restrict__ fb2,
                                               _Float16* __restrict__ tables) {
    __shared__ _Float16 R[64][40];    // rbf rows for 64 bins
    __shared__ _Float16 T[64][136];
    const int tid = threadIdx.x;
    const int wave = tid >> 6, lane = tid & 63;
    const int m = lane & 15, g = lane >> 4;
    const int l = blockIdx.y;
    const int bin0 = blockIdx.x * 64;
    const int c0 = wave * 32;

    // fill rbf LDS: thread tid computes R[tid/4][(tid%4)*8 .. +7]
    {
        int r = tid >> 2, cc0 = (tid & 3) * 8;
        float d = (float)(bin0 + r) * (DMAXF / (float)BINS);
#pragma unroll
        for (int j = 0; j < 8; ++j) {
            float dd = d - (float)(cc0 + j) * CSPACE;
            R[r][cc0 + j] = (_Float16)expf(-GAMMAF * dd * dd);
        }
    }
    __syncthreads();

    f32x4 acc[4][2];
#pragma unroll
    for (int rt = 0; rt < 4; ++rt)
#pragma unroll
        for (int t = 0; t < 2; ++t) acc[rt][t] = (f32x4){0.f, 0.f, 0.f, 0.f};

    // ---- phase A: rbf @ fw1 (single K=32 tile) ----
    {
        half8v a[4];
#pragma unroll
        for (int rt = 0; rt < 4; ++rt)
            a[rt] = *(const half8v*)&R[16 * rt + m][g * 8];
#pragma unroll
        for (int t = 0; t < 2; ++t) {
            int nt = (c0 >> 4) + t;
            half8v b = *(const half8v*)(w1f + (size_t)l * RBF * HID + ((size_t)nt * 64 + lane) * 8);
#pragma unroll
            for (int rt = 0; rt < 4; ++rt)
                acc[rt][t] = __builtin_amdgcn_mfma_f32_16x16x32_f16(a[rt], b, acc[rt][t], 0, 0, 0);
        }
    }
    // epilogue A: +fb1, ssp -> T
    {
        float bc0 = fb1[l * HID + c0 + m], bc1 = fb1[l * HID + c0 + 16 + m];
#pragma unroll
        for (int rt = 0; rt < 4; ++rt)
#pragma unroll
            for (int t = 0; t < 2; ++t) {
                int col = c0 + 16 * t + m;
                float bc = t ? bc1 : bc0;
#pragma unroll
                for (int reg = 0; reg < 4; ++reg)
                    T[16 * rt + 4 * g + reg][col] = (_Float16)sspf(acc[rt][t][reg] + bc);
            }
    }
    __syncthreads();

    // ---- phase B: T @ fw2 ----
#pragma unroll
    for (int rt = 0; rt < 4; ++rt)
#pragma unroll
        for (int t = 0; t < 2; ++t) acc[rt][t] = (f32x4){0.f, 0.f, 0.f, 0.f};
#pragma unroll
    for (int kt = 0; kt < 4; ++kt) {
        half8v a[4];
#pragma unroll
        for (int rt = 0; rt < 4; ++rt)
            a[rt] = *(const half8v*)&T[16 * rt + m][kt * 32 + g * 8];
#pragma unroll
        for (int t = 0; t < 2; ++t) {
            int nt = (c0 >> 4) + t;
            half8v b = *(const half8v*)(w2f + (size_t)l * 16384 + (((size_t)kt * 8 + nt) * 64 + lane) * 8);
#pragma unroll
            for (int rt = 0; rt < 4; ++rt)
                acc[rt][t] = __builtin_amdgcn_mfma_f32_16x16x32_f16(a[rt], b, acc[rt][t], 0, 0, 0);
        }
    }
    __syncthreads();
    {
        float bc0 = fb2[l * HID + c0 + m], bc1 = fb2[l * HID + c0 + 16 + m];
#pragma unroll
        for (int rt = 0; rt < 4; ++rt)
#pragma unroll
            for (int t = 0; t < 2; ++t) {
                int col = c0 + 16 * t + m;
                float bc = t ? bc1 : bc0;
#pragma unroll
                for (int reg = 0; reg < 4; ++reg)
                    T[16 * rt + 4 * g + reg][col] = (_Float16)(acc[rt][t][reg] + bc);
            }
    }
    __syncthreads();
    _Float16* dst = tables + (size_t)l * (BINS + 1) * HID;
    for (int it = tid; it < 1024; it += 256) {
        int row = it >> 4, cc = (it & 15) * 8;
        int bin = bin0 + row;
        if (bin <= BINS)
            *(half8v*)(dst + (size_t)bin * HID + cc) = *(const half8v*)&T[row][cc];
    }
}

// ---------- per-layer edge pass: one wave per node, 4 edges in flight ----------
// packed-fp16 accumulate (v_pk_fma_f16), fp32 only for final scale
__global__ void k_edge(const int* __restrict__ row_ofs, const unsigned int* __restrict__ epk,
                       const _Float16* __restrict__ h, const _Float16* __restrict__ table,
                       const float* __restrict__ invdeg, _Float16* __restrict__ aggr, int n) {
    int wv = (blockIdx.x * blockDim.x + threadIdx.x) >> 6;
    if (wv >= n) return;
    int lane = threadIdx.x & 63;
    int quarter = lane >> 4;   // 4 edges in flight per wave
    int sub = lane & 15;       // channel block: c = 8*sub .. 8*sub+7
    int beg = row_ofs[wv], end = row_ofs[wv + 1];
    half8v acc;
#pragma unroll
    for (int q = 0; q < 8; ++q) acc[q] = (_Float16)0.f;
    const _Float16* hB = h + 8 * sub;
    const _Float16* tB = table + 8 * sub;
    for (int k = beg + quarter; k < end; k += 4) {
        unsigned int pk = epk[k];
        int j = pk & 0x1FFFF;
        int b = pk >> 17;
        half8v hj = *(const half8v*)(hB + (size_t)j * HID);
        half8v tw = *(const half8v*)(tB + (size_t)b * HID);
        acc += hj * tw;          // 4x v_pk_fma_f16
    }
    // cross-quarter reduce via bit shuffles
    int4 ai = *(int4*)&acc;
#pragma unroll
    for (int o = 32; o >= 16; o >>= 1) {
        int4 oi;
        oi.x = __shfl_xor(ai.x, o);
        oi.y = __shfl_xor(ai.y, o);
        oi.z = __shfl_xor(ai.z, o);
        oi.w = __shfl_xor(ai.w, o);
        half8v ov = *(half8v*)&oi;
        half8v av = *(half8v*)&ai;
        av += ov;
        ai = *(int4*)&av;
    }
    if (quarter == 0) {
        half8v av = *(half8v*)&ai;
        float s = invdeg[wv];
        half8v o;
#pragma unroll
        for (int q = 0; q < 8; ++q) o[q] = (_Float16)((float)av[q] * s);
        *(half8v*)(aggr + (size_t)wv * HID + 8 * sub) = o;
    }
}

// ---------- fused 2-layer MLP via fp16 MFMA ----------
// MODE 0: Y = ssp(X@W1+b1)@W2+b2, stored fp16
// MODE 1: e = ssp(ssp(X@W1+b1)@W2+b2) @ ow3 + ob3 per row, segment-summed into out
template <int MODE>
__global__ __launch_bounds__(256) void k_mlp(const _Float16* __restrict__ X,
                                             const _Float16* __restrict__ W1f,
                                             const float* __restrict__ b1,
                                             const _Float16* __restrict__ W2f,
                                             const float* __restrict__ b2,
                                             _Float16* __restrict__ Y,
                                             const float* __restrict__ ow3,
                                             const float* __restrict__ ob3,
                                             const int* __restrict__ batch,
                                             float* __restrict__ out, int M) {
    __shared__ _Float16 T[64][136];
    const int tid = threadIdx.x;
    const int wave = tid >> 6, lane = tid & 63;
    const int m = lane & 15, g = lane >> 4;
    const int row0 = blockIdx.x * 64;
    const int c0 = wave * 32;               // this wave's output column base

    half8v zfrag;
#pragma unroll
    for (int q = 0; q < 8; ++q) zfrag[q] = (_Float16)0.f;

    f32x4 acc[4][2];
#pragma unroll
    for (int rt = 0; rt < 4; ++rt)
#pragma unroll
        for (int t = 0; t < 2; ++t) acc[rt][t] = (f32x4){0.f, 0.f, 0.f, 0.f};

    // ---- phase 1: X @ W1 ----
#pragma unroll
    for (int kt = 0; kt < 4; ++kt) {
        half8v a[4];
#pragma unroll
        for (int rt = 0; rt < 4; ++rt) {
            int r = row0 + 16 * rt + m;
            a[rt] = (r < M) ? *(const half8v*)(X + (size_t)r * HID + kt * 32 + g * 8) : zfrag;
        }
#pragma unroll
        for (int t = 0; t < 2; ++t) {
            int nt = (c0 >> 4) + t;
            half8v b = *(const half8v*)(W1f + (((size_t)kt * 8 + nt) * 64 + lane) * 8);
#pragma unroll
            for (int rt = 0; rt < 4; ++rt)
                acc[rt][t] = __builtin_amdgcn_mfma_f32_16x16x32_f16(a[rt], b, acc[rt][t], 0, 0, 0);
        }
    }
    // epilogue 1: +b1, ssp, to LDS fp16 (C layout: col=lane&15, row=(lane>>4)*4+reg)
    {
        float bc0 = b1[c0 + m], bc1 = b1[c0 + 16 + m];
#pragma unroll
        for (int rt = 0; rt < 4; ++rt)
#pragma unroll
            for (int t = 0; t < 2; ++t) {
                int col = c0 + 16 * t + m;
                float bc = t ? bc1 : bc0;
#pragma unroll
                for (int reg = 0; reg < 4; ++reg)
                    T[16 * rt + 4 * g + reg][col] = (_Float16)sspf(acc[rt][t][reg] + bc);
            }
    }
    __syncthreads();

    // ---- phase 2: T @ W2 ----
#pragma unroll
    for (int rt = 0; rt < 4; ++rt)
#pragma unroll
        for (int t = 0; t < 2; ++t) acc[rt][t] = (f32x4){0.f, 0.f, 0.f, 0.f};

#pragma unroll
    for (int kt = 0; kt < 4; ++kt) {
        half8v a[4];
#pragma unroll
        for (int rt = 0; rt < 4; ++rt)
            a[rt] = *(const half8v*)&T[16 * rt + m][kt * 32 + g * 8];
#pragma unroll
        for (int t = 0; t < 2; ++t) {
            int nt = (c0 >> 4) + t;
            half8v b = *(const half8v*)(W2f + (((size_t)kt * 8 + nt) * 64 + lane) * 8);
#pragma unroll
            for (int rt = 0; rt < 4; ++rt)
                acc[rt][t] = __builtin_amdgcn_mfma_f32_16x16x32_f16(a[rt], b, acc[rt][t], 0, 0, 0);
        }
    }

    if (MODE == 0) {
        __syncthreads();   // all T reads done before overwrite
        float bc0 = b2[c0 + m], bc1 = b2[c0 + 16 + m];
#pragma unroll
        for (int rt = 0; rt < 4; ++rt)
#pragma unroll
            for (int t = 0; t < 2; ++t) {
                int col = c0 + 16 * t + m;
                float bc = t ? bc1 : bc0;
#pragma unroll
                for (int reg = 0; reg < 4; ++reg)
                    T[16 * rt + 4 * g + reg][col] = (_Float16)(acc[rt][t][reg] + bc);
            }
        __syncthreads();
        for (int it = tid; it < 1024; it += 256) {
            int row = it >> 4, cc = (it & 15) * 8;
            int r = row0 + row;
            if (r < M)
                *(half8v*)(Y + (size_t)r * HID + cc) = *(const half8v*)&T[row][cc];
        }
    } else {
        // fused energy: e_row = ssp(acc+b2) . ow3, fp32 throughout
        __shared__ float ea[4][64];
        __shared__ float ev[64];
        __shared__ int   bv[64];
        float bc0 = b2[c0 + m], bc1 = b2[c0 + 16 + m];
        float w0 = ow3[c0 + m], w1 = ow3[c0 + 16 + m];
#pragma unroll
        for (int rt = 0; rt < 4; ++rt) {
#pragma unroll
            for (int reg = 0; reg < 4; ++reg) {
                float p = sspf(acc[rt][0][reg] + bc0) * w0
                        + sspf(acc[rt][1][reg] + bc1) * w1;
                p += __shfl_xor(p, 1);
                p += __shfl_xor(p, 2);
                p += __shfl_xor(p, 4);
                p += __shfl_xor(p, 8);
                if (m == 0) ea[wave][16 * rt + 4 * g + reg] = p;
            }
        }
        __syncthreads();
        if (tid < 64) {
            int r = tid, row = row0 + r;
            float e = ea[0][r] + ea[1][r] + ea[2][r] + ea[3][r] + ob3[0];
            int bid = (row < M) ? batch[row] : -1;
            ev[r] = (row < M) ? e : 0.f;
            bv[r] = bid;
        }
        __syncthreads();
        if (tid < 64) {
            int r = tid, bid = bv[r];
            if (bid >= 0 && (r == 0 || bv[r - 1] != bid)) {
                float s = 0.f;
                for (int k = r; k < 64 && bv[k] == bid; ++k) s += ev[k];
                atomicAdd(&out[bid], s);
            }
        }
    }
}

extern "C" void kernel_launch(void* const* d_in, const int* in_sizes, int n_in,
                              void* d_out, int out_size, void* d_ws, size_t ws_size,
                              hipStream_t stream) {
    const int*   z     = (const int*)d_in[0];
    const float* pos   = (const float*)d_in[1];
    const int*   ei    = (const int*)d_in[2];
    const int*   batch = (const int*)d_in[3];
    const float* embed = (const float*)d_in[4];
    const float* fw1   = (const float*)d_in[5];
    const float* fb1   = (const float*)d_in[6];
    const float* fw2   = (const float*)d_in[7];
    const float* fb2   = (const float*)d_in[8];
    const float* uw1   = (const float*)d_in[9];
    const float* ub1   = (const float*)d_in[10];
    const float* uw2   = (const float*)d_in[11];
    const float* ub2   = (const float*)d_in[12];
    const float* ow1   = (const float*)d_in[13];
    const float* ob1   = (const float*)d_in[14];
    const float* ow2   = (const float*)d_in[15];
    const float* ob2   = (const float*)d_in[16];
    const float* ow3   = (const float*)d_in[17];
    const float* ob3   = (const float*)d_in[18];

    const int N = in_sizes[0];
    const int E = in_sizes[2] / 2;
    const int NB = (N + SB - 1) / SB;

    // workspace carve
    char* p = (char*)d_ws;
    auto alloc = [&](size_t bytes) {
        char* r = p;
        p += (bytes + 255) & ~(size_t)255;
        return r;
    };
    _Float16* h       = (_Float16*)alloc((size_t)(N + 64) * HID * 2);
    _Float16* aggr    = (_Float16*)alloc((size_t)(N + 64) * HID * 2);
    unsigned int* epk = (unsigned int*)alloc((size_t)E * 4);
    int*      counts  = (int*)alloc((size_t)N * 4);
    int*      row_ofs = (int*)alloc((size_t)(N + 1) * 4);
    int*      cursor  = (int*)alloc((size_t)N * 4);
    int*      pre     = (int*)alloc((size_t)N * 4);
    int*      bsums   = (int*)alloc((size_t)1024 * 4);
    float*    invdeg  = (float*)alloc((size_t)N * 4);
    _Float16* tab16   = (_Float16*)alloc((size_t)NL * (BINS + 1) * HID * 2);
    _Float16* w1tf    = (_Float16*)alloc((size_t)NL * RBF * HID * 2);
    _Float16* w2tf    = (_Float16*)alloc((size_t)NL * 16384 * 2);
    _Float16* uw1b    = (_Float16*)alloc((size_t)NL * 16384 * 2);
    _Float16* uw2b    = (_Float16*)alloc((size_t)NL * 16384 * 2);
    _Float16* ow1b    = (_Float16*)alloc((size_t)16384 * 2);
    _Float16* ow2b    = (_Float16*)alloc((size_t)16384 * 2);

    const int TB = 256;
    hipMemsetAsync(counts, 0, (size_t)N * 4, stream);
    hipMemsetAsync(d_out, 0, (size_t)out_size * sizeof(float), stream);

    k_count<<<(E + TB - 1) / TB, TB, 0, stream>>>(ei, counts, E);
    k_scan1<<<NB, SB, 0, stream>>>(counts, pre, bsums, N);
    k_scan2<<<1, 1024, 0, stream>>>(bsums, NB);
    k_scan3<<<NB, SB, 0, stream>>>(pre, bsums, counts, row_ofs, cursor, N);
    k_scatter<<<(E + TB - 1) / TB, TB, 0, stream>>>(ei, pos, cursor, epk, E);
    int tot4 = N * 32;
    k_hinit<<<(tot4 + TB - 1) / TB, TB, 0, stream>>>(z, embed, h, tot4);
    k_invdeg<<<(N + TB - 1) / TB, TB, 0, stream>>>(counts, invdeg, N);
    k_wpack32<<<dim3(8, NL), 64, 0, stream>>>(fw1, w1tf);
    k_wpack<<<dim3(32, NL), 64, 0, stream>>>(fw2, w2tf);
    k_wpack<<<dim3(32, NL), 64, 0, stream>>>(uw1, uw1b);
    k_wpack<<<dim3(32, NL), 64, 0, stream>>>(uw2, uw2b);
    k_wpack<<<dim3(32, 1), 64, 0, stream>>>(ow1, ow1b);
    k_wpack<<<dim3(32, 1), 64, 0, stream>>>(ow2, ow2b);
    k_tabmm<<<dim3((BINS + 1 + 63) / 64, NL), 256, 0, stream>>>(w1tf, fb1, w2tf, fb2, tab16);

    int eblocks = (N + 3) / 4;      // 4 waves per 256-thread block, 1 wave per node
    int mblocks = (N + 63) / 64;

    for (int l = 0; l < NL; ++l) {
        k_edge<<<eblocks, TB, 0, stream>>>(row_ofs, epk, h,
                                           tab16 + (size_t)l * (BINS + 1) * HID,
                                           invdeg, aggr, N);
        k_mlp<0><<<mblocks, TB, 0, stream>>>(aggr,
                                             uw1b + (size_t)l * 16384, ub1 + (size_t)l * HID,
                                             uw2b + (size_t)l * 16384, ub2 + (size_t)l * HID,
                                             h, nullptr, nullptr, nullptr, nullptr, N);
    }
    // output block fused with energy reduction
    k_mlp<1><<<mblocks, TB, 0, stream>>>(h, ow1b, ob1, ow2b, ob2, nullptr,
                                         ow3, ob3, batch, (float*)d_out, N);
}

// Round 6
// 634.033 us; speedup vs baseline: 2.3260x; 1.1440x over previous
//
#include <hip/hip_runtime.h>
#include <math.h>

#define HID 128
#define RBF 32
#define NL 6
#define BINS 4096
#define DMAXF 5.0f
#define INV_STEP (4096.0f / 5.0f)
#define GAMMAF 32.0f
#define CSPACE (4.0f / 31.0f)   // linspace(0,4,32) spacing

typedef _Float16 half8v __attribute__((ext_vector_type(8)));
typedef _Float16 half4v __attribute__((ext_vector_type(4)));
typedef float f32x4 __attribute__((ext_vector_type(4)));

// softplus(x)-0.5 via HW transcendentals (v_exp_f32/v_log_f32), ~6 VALU ops
__device__ __forceinline__ float sspf(float x) {
    return fmaxf(x, 0.0f) + __logf(1.0f + __expf(-fabsf(x))) - 0.5f;
}

// ---------- one-time preprocessing ----------

__global__ void k_count(const int* __restrict__ ei, int* __restrict__ counts, int E_) {
    int e = blockIdx.x * blockDim.x + threadIdx.x;
    if (e >= E_) return;
    atomicAdd(&counts[ei[e]], 1);
}

// hierarchical exclusive scan: 256-elem blocks -> block sums -> apply
#define SB 256
__global__ void k_scan1(const int* __restrict__ counts, int* __restrict__ pre,
                        int* __restrict__ bsums, int n) {
    __shared__ int s[SB];
    int tid = threadIdx.x;
    int g = blockIdx.x * SB + tid;
    int v = (g < n) ? counts[g] : 0;
    s[tid] = v;
    __syncthreads();
    for (int off = 1; off < SB; off <<= 1) {
        int t = (tid >= off) ? s[tid - off] : 0;
        __syncthreads();
        s[tid] += t;
        __syncthreads();
    }
    if (g < n) pre[g] = s[tid] - v;   // exclusive within block
    if (tid == SB - 1) bsums[blockIdx.x] = s[tid];
}

__global__ void k_scan2(int* __restrict__ bsums, int nb) {
    __shared__ int s[1024];
    int tid = threadIdx.x;
    int v = (tid < nb) ? bsums[tid] : 0;
    s[tid] = v;
    __syncthreads();
    for (int off = 1; off < 1024; off <<= 1) {
        int t = (tid >= off) ? s[tid - off] : 0;
        __syncthreads();
        s[tid] += t;
        __syncthreads();
    }
    if (tid < nb) bsums[tid] = s[tid] - v;  // exclusive block offsets
}

__global__ void k_scan3(const int* __restrict__ pre, const int* __restrict__ bsums,
                        const int* __restrict__ counts, int* __restrict__ row_ofs,
                        int* __restrict__ cursor, int n) {
    int g = blockIdx.x * SB + threadIdx.x;
    if (g >= n) return;
    int r = pre[g] + bsums[g >> 8];
    row_ofs[g] = r;
    cursor[g] = r;
    if (g == n - 1) row_ofs[n] = r + counts[g];
}

// compute dist, quantize to bin, pack (j | bin<<17) into CSR order
__global__ void k_scatter(const int* __restrict__ ei, const float* __restrict__ pos,
                          int* __restrict__ cursor, unsigned int* __restrict__ epk, int E_) {
    int e = blockIdx.x * blockDim.x + threadIdx.x;
    if (e >= E_) return;
    int i = ei[e], j = ei[E_ + e];
    float dx = pos[3 * i]     - pos[3 * j];
    float dy = pos[3 * i + 1] - pos[3 * j + 1];
    float dz = pos[3 * i + 2] - pos[3 * j + 2];
    float d = sqrtf(dx * dx + dy * dy + dz * dz);
    float t = fminf(d, DMAXF) * INV_STEP;
    unsigned int b = (unsigned int)(t + 0.5f);   // nearest bin, 0..4096
    int p = atomicAdd(&cursor[i], 1);
    epk[p] = (unsigned int)j | (b << 17);
}

// h (fp16) init from embedding
__global__ void k_hinit(const int* __restrict__ z, const float* __restrict__ embed,
                        _Float16* __restrict__ h, int total4) {
    int idx = blockIdx.x * blockDim.x + threadIdx.x;
    if (idx >= total4) return;
    int node = idx >> 5, q = idx & 31;
    float4 v = ((const float4*)embed)[(size_t)z[node] * 32 + q];
    half4v o;
    o[0] = (_Float16)v.x; o[1] = (_Float16)v.y;
    o[2] = (_Float16)v.z; o[3] = (_Float16)v.w;
    *(half4v*)(h + (size_t)node * HID + q * 4) = o;
}

__global__ void k_invdeg(const int* __restrict__ counts, float* __restrict__ invdeg, int n) {
    int i = blockIdx.x * blockDim.x + threadIdx.x;
    if (i < n) invdeg[i] = 1.0f / fmaxf((float)counts[i], 1.0f);
}

// pack a 128x128 fp32 row-major weight matrix into MFMA B-fragment order (fp16).
// dst[((kt*8+nt)*64 + lane)*8 + j] = W[32*kt + 8*(lane>>4) + j][16*nt + (lane&15)]
__global__ void k_wpack(const float* __restrict__ W, _Float16* __restrict__ dst) {
    int b = blockIdx.x;               // kt*8+nt, 0..31
    int kt = b >> 3, nt = b & 7;
    int lane = threadIdx.x;           // 64
    int m = lane & 15, g = lane >> 4;
    const float* src = W + (size_t)blockIdx.y * 16384;
    _Float16* d = dst + (size_t)blockIdx.y * 16384 + ((size_t)b * 64 + lane) * 8;
#pragma unroll
    for (int j = 0; j < 8; ++j)
        d[j] = (_Float16)src[(32 * kt + 8 * g + j) * 128 + 16 * nt + m];
}

// pack a 32x128 fp32 weight (fw1 layer) into single-kt B-fragment order (fp16)
__global__ void k_wpack32(const float* __restrict__ W, _Float16* __restrict__ dst) {
    int nt = blockIdx.x;              // 0..7
    int lane = threadIdx.x;           // 64
    int m = lane & 15, g = lane >> 4;
    const float* src = W + (size_t)blockIdx.y * RBF * HID;
    _Float16* d = dst + (size_t)blockIdx.y * RBF * HID + ((size_t)nt * 64 + lane) * 8;
#pragma unroll
    for (int j = 0; j < 8; ++j)
        d[j] = (_Float16)src[(8 * g + j) * 128 + 16 * nt + m];
}

// shared GEMM helper: acc += A(64x32 LDS tile at kt offsets) @ Wf(frag-packed)
__device__ __forceinline__ void gemm128(const _Float16 (*A)[136], const _Float16* __restrict__ Wf,
                                        int lane, int c0, f32x4 acc[4][2]) {
    const int m = lane & 15, g = lane >> 4;
#pragma unroll
    for (int kt = 0; kt < 4; ++kt) {
        half8v a[4];
#pragma unroll
        for (int rt = 0; rt < 4; ++rt)
            a[rt] = *(const half8v*)&A[16 * rt + m][kt * 32 + g * 8];
#pragma unroll
        for (int t = 0; t < 2; ++t) {
            int nt = (c0 >> 4) + t;
            half8v b = *(const half8v*)(Wf + (((size_t)kt * 8 + nt) * 64 + lane) * 8);
#pragma unroll
            for (int rt = 0; rt < 4; ++rt)
                acc[rt][t] = __builtin_amdgcn_mfma_f32_16x16x32_f16(a[rt], b, acc[rt][t], 0, 0, 0);
        }
    }
}

__device__ __forceinline__ void zacc(f32x4 acc[4][2]) {
#pragma unroll
    for (int rt = 0; rt < 4; ++rt)
#pragma unroll
        for (int t = 0; t < 2; ++t) acc[rt][t] = (f32x4){0.f, 0.f, 0.f, 0.f};
}

// epilogue: dst[C-layout] = (ssp?)(acc + bias)
template <bool SSP>
__device__ __forceinline__ void epi(_Float16 (*dst)[136], const float* __restrict__ bias,
                                    int lane, int c0, const f32x4 acc[4][2]) {
    const int m = lane & 15, g = lane >> 4;
    float bc0 = bias[c0 + m], bc1 = bias[c0 + 16 + m];
#pragma unroll
    for (int rt = 0; rt < 4; ++rt)
#pragma unroll
        for (int t = 0; t < 2; ++t) {
            int col = c0 + 16 * t + m;
            float bc = t ? bc1 : bc0;
#pragma unroll
            for (int reg = 0; reg < 4; ++reg) {
                float v = acc[rt][t][reg] + bc;
                dst[16 * rt + 4 * g + reg][col] = (_Float16)(SSP ? sspf(v) : v);
            }
        }
}

// ---------- MFMA table build: tables[l][bin][c] = ssp(rbf@fw1+fb1)@fw2+fb2 ----------
__global__ __launch_bounds__(256) void k_tabmm(const _Float16* __restrict__ w1f,
                                               const float* __restrict__ fb1,
                                               const _Float16* __restrict__ w2f,
                                               const float* __restrict__ fb2,
                                               _Float16* __restrict__ tables) {
    __shared__ _Float16 R[64][40];    // rbf rows for 64 bins
    __shared__ _Float16 T[64][136];
    const int tid = threadIdx.x;
    const int wave = tid >> 6, lane = tid & 63;
    const int m = lane & 15, g = lane >> 4;
    const int l = blockIdx.y;
    const int bin0 = blockIdx.x * 64;
    const int c0 = wave * 32;

    {
        int r = tid >> 2, cc0 = (tid & 3) * 8;
        float d = (float)(bin0 + r) * (DMAXF / (float)BINS);
#pragma unroll
        for (int j = 0; j < 8; ++j) {
            float dd = d - (float)(cc0 + j) * CSPACE;
            R[r][cc0 + j] = (_Float16)__expf(-GAMMAF * dd * dd);
        }
    }
    __syncthreads();

    f32x4 acc[4][2];
    zacc(acc);
    // phase A: rbf @ fw1 (single K=32 tile)
    {
        half8v a[4];
#pragma unroll
        for (int rt = 0; rt < 4; ++rt)
            a[rt] = *(const half8v*)&R[16 * rt + m][g * 8];
#pragma unroll
        for (int t = 0; t < 2; ++t) {
            int nt = (c0 >> 4) + t;
            half8v b = *(const half8v*)(w1f + (size_t)l * RBF * HID + ((size_t)nt * 64 + lane) * 8);
#pragma unroll
            for (int rt = 0; rt < 4; ++rt)
                acc[rt][t] = __builtin_amdgcn_mfma_f32_16x16x32_f16(a[rt], b, acc[rt][t], 0, 0, 0);
        }
    }
    epi<true>(T, fb1 + l * HID, lane, c0, acc);
    __syncthreads();

    zacc(acc);
    gemm128(T, w2f + (size_t)l * 16384, lane, c0, acc);
    __syncthreads();
    epi<false>(T, fb2 + l * HID, lane, c0, acc);
    __syncthreads();
    _Float16* dst = tables + (size_t)l * (BINS + 1) * HID;
    for (int it = tid; it < 1024; it += 256) {
        int row = it >> 4, cc = (it & 15) * 8;
        int bin = bin0 + row;
        if (bin <= BINS)
            *(half8v*)(dst + (size_t)bin * HID + cc) = *(const half8v*)&T[row][cc];
    }
}

// ---------- fused layer: edge-aggregate (into LDS) + 2-GEMM MLP ----------
// FINAL=0: h' = ssp(aggr@W1+b1)@W2+b2 -> Y
// FINAL=1: continue with output block ssp/ssp/dot(ow3) and segment-sum energy
template <int FINAL>
__global__ __launch_bounds__(256) void k_layer(
        const int* __restrict__ row_ofs, const unsigned int* __restrict__ epk,
        const _Float16* __restrict__ h, const _Float16* __restrict__ table,
        const float* __restrict__ invdeg,
        const _Float16* __restrict__ W1f, const float* __restrict__ b1,
        const _Float16* __restrict__ W2f, const float* __restrict__ b2,
        _Float16* __restrict__ Y,
        const _Float16* __restrict__ OW1f, const float* __restrict__ ob1,
        const _Float16* __restrict__ OW2f, const float* __restrict__ ob2,
        const float* __restrict__ ow3, const float* __restrict__ ob3,
        const int* __restrict__ batch, float* __restrict__ out, int n) {
    __shared__ _Float16 U[64][136];
    __shared__ _Float16 T[64][136];
    const int tid = threadIdx.x;
    const int wave = tid >> 6, lane = tid & 63;
    const int quarter = lane >> 4, sub = lane & 15;
    const int row0 = blockIdx.x * 64;
    const int c0 = wave * 32;

    // ---- edge phase: each wave aggregates 16 nodes, 4 edges in flight ----
    const _Float16* hB = h + 8 * sub;
    const _Float16* tB = table + 8 * sub;
    for (int idx = 0; idx < 16; ++idx) {
        int r = 16 * wave + idx;
        int node = row0 + r;
        int beg = 0, end = 0;
        if (node < n) { beg = row_ofs[node]; end = row_ofs[node + 1]; }
        half8v acc;
#pragma unroll
        for (int q = 0; q < 8; ++q) acc[q] = (_Float16)0.f;
        for (int k = beg + quarter; k < end; k += 4) {
            unsigned int pk = epk[k];
            int j = pk & 0x1FFFF;
            int b = pk >> 17;
            half8v hj = *(const half8v*)(hB + (size_t)j * HID);
            half8v tw = *(const half8v*)(tB + (size_t)b * HID);
            acc += hj * tw;          // v_pk_fma_f16
        }
        int4 ai = *(int4*)&acc;
#pragma unroll
        for (int o = 32; o >= 16; o >>= 1) {
            int4 oi;
            oi.x = __shfl_xor(ai.x, o);
            oi.y = __shfl_xor(ai.y, o);
            oi.z = __shfl_xor(ai.z, o);
            oi.w = __shfl_xor(ai.w, o);
            half8v ov = *(half8v*)&oi;
            half8v av = *(half8v*)&ai;
            av += ov;
            ai = *(int4*)&av;
        }
        if (quarter == 0) {
            half8v av = *(half8v*)&ai;
            float s = (node < n) ? invdeg[node] : 0.f;
            half8v o;
#pragma unroll
            for (int q = 0; q < 8; ++q) o[q] = (_Float16)((float)av[q] * s);
            *(half8v*)&U[r][8 * sub] = o;
        }
    }
    __syncthreads();

    // ---- GEMM 1: U @ W1, ssp -> T ----
    f32x4 acc[4][2];
    zacc(acc);
    gemm128(U, W1f, lane, c0, acc);
    epi<true>(T, b1, lane, c0, acc);
    __syncthreads();

    // ---- GEMM 2: T @ W2 ----
    zacc(acc);
    gemm128(T, W2f, lane, c0, acc);

    if (FINAL == 0) {
        epi<false>(U, b2, lane, c0, acc);   // U dead since last sync -> no barrier needed
        __syncthreads();
        for (int it = tid; it < 1024; it += 256) {
            int row = it >> 4, cc = (it & 15) * 8;
            int r = row0 + row;
            if (r < n)
                *(half8v*)(Y + (size_t)r * HID + cc) = *(const half8v*)&U[row][cc];
        }
    } else {
        // h6 = acc + b2 -> U
        epi<false>(U, b2, lane, c0, acc);
        __syncthreads();
        // GEMM 3: ssp(U) ... note U already has raw h6; output block layer 1
        zacc(acc);
        gemm128(U, OW1f, lane, c0, acc);
        epi<true>(T, ob1, lane, c0, acc);
        __syncthreads();
        // GEMM 4: T @ OW2
        zacc(acc);
        gemm128(T, OW2f, lane, c0, acc);
        // energy: e_row = ssp(acc + ob2) . ow3 (+ob3), segment-summed
        __shared__ float ea[4][64];
        __shared__ float ev[64];
        __shared__ int   bv[64];
        const int m = lane & 15, g = lane >> 4;
        float bc0 = ob2[c0 + m], bc1 = ob2[c0 + 16 + m];
        float w0 = ow3[c0 + m], w1 = ow3[c0 + 16 + m];
#pragma unroll
        for (int rt = 0; rt < 4; ++rt) {
#pragma unroll
            for (int reg = 0; reg < 4; ++reg) {
                float p = sspf(acc[rt][0][reg] + bc0) * w0
                        + sspf(acc[rt][1][reg] + bc1) * w1;
                p += __shfl_xor(p, 1);
                p += __shfl_xor(p, 2);
                p += __shfl_xor(p, 4);
                p += __shfl_xor(p, 8);
                if (m == 0) ea[wave][16 * rt + 4 * g + reg] = p;
            }
        }
        __syncthreads();
        if (tid < 64) {
            int r = tid, row = row0 + r;
            float e = ea[0][r] + ea[1][r] + ea[2][r] + ea[3][r] + ob3[0];
            int bid = (row < n) ? batch[row] : -1;
            ev[r] = (row < n) ? e : 0.f;
            bv[r] = bid;
        }
        __syncthreads();
        if (tid < 64) {
            int r = tid, bid = bv[r];
            if (bid >= 0 && (r == 0 || bv[r - 1] != bid)) {
                float s = 0.f;
                for (int k = r; k < 64 && bv[k] == bid; ++k) s += ev[k];
                atomicAdd(&out[bid], s);
            }
        }
    }
}

extern "C" void kernel_launch(void* const* d_in, const int* in_sizes, int n_in,
                              void* d_out, int out_size, void* d_ws, size_t ws_size,
                              hipStream_t stream) {
    const int*   z     = (const int*)d_in[0];
    const float* pos   = (const float*)d_in[1];
    const int*   ei    = (const int*)d_in[2];
    const int*   batch = (const int*)d_in[3];
    const float* embed = (const float*)d_in[4];
    const float* fw1   = (const float*)d_in[5];
    const float* fb1   = (const float*)d_in[6];
    const float* fw2   = (const float*)d_in[7];
    const float* fb2   = (const float*)d_in[8];
    const float* uw1   = (const float*)d_in[9];
    const float* ub1   = (const float*)d_in[10];
    const float* uw2   = (const float*)d_in[11];
    const float* ub2   = (const float*)d_in[12];
    const float* ow1   = (const float*)d_in[13];
    const float* ob1   = (const float*)d_in[14];
    const float* ow2   = (const float*)d_in[15];
    const float* ob2   = (const float*)d_in[16];
    const float* ow3   = (const float*)d_in[17];
    const float* ob3   = (const float*)d_in[18];

    const int N = in_sizes[0];
    const int E = in_sizes[2] / 2;
    const int NB = (N + SB - 1) / SB;

    // workspace carve
    char* p = (char*)d_ws;
    auto alloc = [&](size_t bytes) {
        char* r = p;
        p += (bytes + 255) & ~(size_t)255;
        return r;
    };
    _Float16* h       = (_Float16*)alloc((size_t)(N + 64) * HID * 2);
    _Float16* h2      = (_Float16*)alloc((size_t)(N + 64) * HID * 2);
    unsigned int* epk = (unsigned int*)alloc((size_t)E * 4);
    int*      counts  = (int*)alloc((size_t)N * 4);
    int*      row_ofs = (int*)alloc((size_t)(N + 1) * 4);
    int*      cursor  = (int*)alloc((size_t)N * 4);
    int*      pre     = (int*)alloc((size_t)N * 4);
    int*      bsums   = (int*)alloc((size_t)1024 * 4);
    float*    invdeg  = (float*)alloc((size_t)N * 4);
    _Float16* tab16   = (_Float16*)alloc((size_t)NL * (BINS + 1) * HID * 2);
    _Float16* w1tf    = (_Float16*)alloc((size_t)NL * RBF * HID * 2);
    _Float16* w2tf    = (_Float16*)alloc((size_t)NL * 16384 * 2);
    _Float16* uw1b    = (_Float16*)alloc((size_t)NL * 16384 * 2);
    _Float16* uw2b    = (_Float16*)alloc((size_t)NL * 16384 * 2);
    _Float16* ow1b    = (_Float16*)alloc((size_t)16384 * 2);
    _Float16* ow2b    = (_Float16*)alloc((size_t)16384 * 2);

    const int TB = 256;
    hipMemsetAsync(counts, 0, (size_t)N * 4, stream);
    hipMemsetAsync(d_out, 0, (size_t)out_size * sizeof(float), stream);

    k_count<<<(E + TB - 1) / TB, TB, 0, stream>>>(ei, counts, E);
    k_scan1<<<NB, SB, 0, stream>>>(counts, pre, bsums, N);
    k_scan2<<<1, 1024, 0, stream>>>(bsums, NB);
    k_scan3<<<NB, SB, 0, stream>>>(pre, bsums, counts, row_ofs, cursor, N);
    k_scatter<<<(E + TB - 1) / TB, TB, 0, stream>>>(ei, pos, cursor, epk, E);
    int tot4 = N * 32;
    k_hinit<<<(tot4 + TB - 1) / TB, TB, 0, stream>>>(z, embed, h, tot4);
    k_invdeg<<<(N + TB - 1) / TB, TB, 0, stream>>>(counts, invdeg, N);
    k_wpack32<<<dim3(8, NL), 64, 0, stream>>>(fw1, w1tf);
    k_wpack<<<dim3(32, NL), 64, 0, stream>>>(fw2, w2tf);
    k_wpack<<<dim3(32, NL), 64, 0, stream>>>(uw1, uw1b);
    k_wpack<<<dim3(32, NL), 64, 0, stream>>>(uw2, uw2b);
    k_wpack<<<dim3(32, 1), 64, 0, stream>>>(ow1, ow1b);
    k_wpack<<<dim3(32, 1), 64, 0, stream>>>(ow2, ow2b);
    k_tabmm<<<dim3((BINS + 1 + 63) / 64, NL), 256, 0, stream>>>(w1tf, fb1, w2tf, fb2, tab16);

    int mblocks = (N + 63) / 64;

    _Float16* cur = h;
    _Float16* nxt = h2;
    for (int l = 0; l < NL - 1; ++l) {
        k_layer<0><<<mblocks, TB, 0, stream>>>(row_ofs, epk, cur,
                                               tab16 + (size_t)l * (BINS + 1) * HID, invdeg,
                                               uw1b + (size_t)l * 16384, ub1 + (size_t)l * HID,
                                               uw2b + (size_t)l * 16384, ub2 + (size_t)l * HID,
                                               nxt,
                                               nullptr, nullptr, nullptr, nullptr,
                                               nullptr, nullptr, nullptr, nullptr, N);
        _Float16* tmp = cur; cur = nxt; nxt = tmp;
    }
    // last layer fused with output block + energy reduction
    k_layer<1><<<mblocks, TB, 0, stream>>>(row_ofs, epk, cur,
                                           tab16 + (size_t)(NL - 1) * (BINS + 1) * HID, invdeg,
                                           uw1b + (size_t)(NL - 1) * 16384, ub1 + (size_t)(NL - 1) * HID,
                                           uw2b + (size_t)(NL - 1) * 16384, ub2 + (size_t)(NL - 1) * HID,
                                           nullptr,
                                           ow1b, ob1, ow2b, ob2,
                                           ow3, ob3, batch, (float*)d_out, N);
}